// Round 1
// baseline (443.943 us; speedup 1.0000x reference)
//
#include <hip/hip_runtime.h>

// ---------------------------------------------------------------------------
// GroupAgent fused pipeline, MI355X (gfx950), fp16 MFMA + f32 accumulate.
// Stages:
//   1. x1 = relu(x @ fc1_w + fc1_b)
//   2. GRU cell -> hn   (fused: both 768-col GEMMs + gates in one kernel)
//   3. t = relu(hn @ hg_w1 + hg_b1)
//   4. g = tanh(t @ hg_w2 + hg_b2)
//   5. q = b_dyn + einsum(hn, g @ hw_w + hw_b)   (fused, w_dyn never stored)
// Weights pre-transposed to f16 [col][k] so every MFMA fragment is a
// contiguous half8 load.
// ---------------------------------------------------------------------------

typedef _Float16 half8 __attribute__((ext_vector_type(8)));
typedef float f32x4 __attribute__((ext_vector_type(4)));

#define MFMA16(a, b, c) __builtin_amdgcn_mfma_f32_16x16x32_f16((a), (b), (c), 0, 0, 0)

constexpr int NROWS = 16384;
constexpr int DIM = 256;   // D_IN = H = E = 256
constexpr int NACT = 32;   // n_actions

__device__ __forceinline__ float sigmoidf_(float x) {
    return 1.0f / (1.0f + __expf(-x));
}

// ---------------- prep: f32 -> f16 elementwise ----------------
__global__ void cvt_kernel(const float* __restrict__ in, _Float16* __restrict__ out, int n) {
    int i = (blockIdx.x * blockDim.x + threadIdx.x) * 4;
    if (i < n) {
        float4 v = *reinterpret_cast<const float4*>(in + i);
        out[i + 0] = (_Float16)v.x;
        out[i + 1] = (_Float16)v.y;
        out[i + 2] = (_Float16)v.z;
        out[i + 3] = (_Float16)v.w;
    }
}

// ---------------- prep: transpose f32 [K][C] -> f16 [C][K] ----------------
__global__ void transpose_kernel(const float* __restrict__ in, _Float16* __restrict__ out,
                                 int K, int C) {
    __shared__ float tile[32][33];
    int kb = blockIdx.x * 32, cb = blockIdx.y * 32;
    int tx = threadIdx.x, ty = threadIdx.y;  // 32 x 8
#pragma unroll
    for (int i = ty; i < 32; i += 8) tile[i][tx] = in[(kb + i) * C + (cb + tx)];
    __syncthreads();
#pragma unroll
    for (int i = ty; i < 32; i += 8) out[(cb + i) * K + (kb + tx)] = (_Float16)tile[tx][i];
}

// ---------------- generic GEMM + bias + activation ----------------
// C[M][NC] = act(A[M][256] @ W + bias), W given transposed as Wt[NC][256].
// grid (M/64, NC/64), block 256 = 4 waves; wave = 16 rows x 64 cols.
template <int ACT>  // 0 none, 1 relu, 2 tanh
__global__ __launch_bounds__(256) void gemm_act_kernel(
    const _Float16* __restrict__ Am, const _Float16* __restrict__ Wt,
    const float* __restrict__ bias, _Float16* __restrict__ out16, int NC) {
    const int K = DIM;
    int wave = threadIdx.x >> 6, lane = threadIdx.x & 63;
    int r = lane & 15, kg = lane >> 4;
    int row0 = blockIdx.x * 64 + wave * 16;
    int col0 = blockIdx.y * 64;

    f32x4 z = {0.f, 0.f, 0.f, 0.f};
    f32x4 acc[4] = {z, z, z, z};
    const _Float16* ap = Am + (row0 + r) * K + kg * 8;
#pragma unroll
    for (int kb = 0; kb < K; kb += 32) {
        half8 a = *reinterpret_cast<const half8*>(ap + kb);
#pragma unroll
        for (int j = 0; j < 4; j++) {
            half8 b = *reinterpret_cast<const half8*>(Wt + (col0 + j * 16 + r) * K + kb + kg * 8);
            acc[j] = MFMA16(a, b, acc[j]);
        }
    }
#pragma unroll
    for (int j = 0; j < 4; j++) {
        int cc = col0 + j * 16 + r;
        float bv = bias[cc];
#pragma unroll
        for (int i = 0; i < 4; i++) {
            int rr = row0 + kg * 4 + i;
            float v = acc[j][i] + bv;
            if (ACT == 1) v = fmaxf(v, 0.0f);
            if (ACT == 2) v = tanhf(v);
            out16[rr * NC + cc] = (_Float16)v;
        }
    }
}

// ---------------- fused GRU cell ----------------
// gi = x1 @ w_ih + b_ih ; gh = h @ w_hh + b_hh (gate order r,z,n)
// hn = (1-z)*tanh(i_n + r*h_n) + z*h
// grid (M/64, 2), block 256; wave = 16 rows; blockIdx.y splits the 16 col-chunks.
__global__ __launch_bounds__(256) void gru_kernel(
    const _Float16* __restrict__ x1, const _Float16* __restrict__ h16,
    const float* __restrict__ hf, const _Float16* __restrict__ wiht,
    const _Float16* __restrict__ whht, const float* __restrict__ bih,
    const float* __restrict__ bhh, _Float16* __restrict__ hn16,
    float* __restrict__ hnf) {
    int wave = threadIdx.x >> 6, lane = threadIdx.x & 63;
    int r = lane & 15, kg = lane >> 4;
    int row0 = blockIdx.x * 64 + wave * 16;

    for (int c16 = blockIdx.y * 8; c16 < blockIdx.y * 8 + 8; c16++) {
        int cc = c16 * 16 + r;  // hn column this lane owns
        f32x4 z4 = {0.f, 0.f, 0.f, 0.f};
        f32x4 air = z4, aiz = z4, ain = z4, ahr = z4, ahz = z4, ahn = z4;
#pragma unroll
        for (int kb = 0; kb < 256; kb += 32) {
            int ko = kb + kg * 8;
            half8 ax = *reinterpret_cast<const half8*>(x1 + (row0 + r) * 256 + ko);
            half8 ah = *reinterpret_cast<const half8*>(h16 + (row0 + r) * 256 + ko);
            half8 bir = *reinterpret_cast<const half8*>(wiht + (0 + cc) * 256 + ko);
            half8 biz = *reinterpret_cast<const half8*>(wiht + (256 + cc) * 256 + ko);
            half8 bin = *reinterpret_cast<const half8*>(wiht + (512 + cc) * 256 + ko);
            half8 bhr = *reinterpret_cast<const half8*>(whht + (0 + cc) * 256 + ko);
            half8 bhz = *reinterpret_cast<const half8*>(whht + (256 + cc) * 256 + ko);
            half8 bhn = *reinterpret_cast<const half8*>(whht + (512 + cc) * 256 + ko);
            air = MFMA16(ax, bir, air);
            aiz = MFMA16(ax, biz, aiz);
            ain = MFMA16(ax, bin, ain);
            ahr = MFMA16(ah, bhr, ahr);
            ahz = MFMA16(ah, bhz, ahz);
            ahn = MFMA16(ah, bhn, ahn);
        }
        float vbir = bih[cc], vbiz = bih[256 + cc], vbin = bih[512 + cc];
        float vbhr = bhh[cc], vbhz = bhh[256 + cc], vbhn = bhh[512 + cc];
#pragma unroll
        for (int i = 0; i < 4; i++) {
            int rr = row0 + kg * 4 + i;
            float hv = hf[rr * 256 + cc];
            float rg = sigmoidf_(air[i] + vbir + ahr[i] + vbhr);
            float zg = sigmoidf_(aiz[i] + vbiz + ahz[i] + vbhz);
            float nn = tanhf(ain[i] + vbin + rg * (ahn[i] + vbhn));
            float v = (1.0f - zg) * nn + zg * hv;
            hn16[rr * 256 + cc] = (_Float16)v;
            hnf[rr * 256 + cc] = v;
        }
    }
}

// ---------------- fused final stage ----------------
// q[n,a] = sum_h hn[n,h] * (g[n,:] @ hw_w[:, h*32+a] + hw_b[h*32+a])
//        + g[n,:] @ hb_w[:,a] + hb_b[a]
// grid (M/128, 4): blockIdx.y = h-split (64 h each); atomicAdd into zeroed q.
// block 256 = 4 waves; wave = 32 rows (2 row-tiles) x 32 actions.
__global__ __launch_bounds__(256) void final_kernel(
    const _Float16* __restrict__ g16, const _Float16* __restrict__ hwt,
    const float* __restrict__ hwb, const _Float16* __restrict__ hbt,
    const float* __restrict__ hbb, const float* __restrict__ hnf,
    float* __restrict__ q) {
    int wave = threadIdx.x >> 6, lane = threadIdx.x & 63;
    int r = lane & 15, kg = lane >> 4;
    int row0 = blockIdx.x * 128 + wave * 32;  // row tiles at row0, row0+16
    int hbase = blockIdx.y * 64;

    // hoist g fragments for both row tiles (whole K=256)
    half8 ga0[8], ga1[8];
#pragma unroll
    for (int kb = 0; kb < 8; kb++) {
        ga0[kb] = *reinterpret_cast<const half8*>(g16 + (row0 + r) * 256 + kb * 32 + kg * 8);
        ga1[kb] = *reinterpret_cast<const half8*>(g16 + (row0 + 16 + r) * 256 + kb * 32 + kg * 8);
    }

    f32x4 z4 = {0.f, 0.f, 0.f, 0.f};
    f32x4 q00 = z4, q01 = z4, q10 = z4, q11 = z4;  // [rowtile][acttile]

    if (blockIdx.y == 0) {  // fuse b_dyn = g @ hb_w + hb_b
#pragma unroll
        for (int kb = 0; kb < 8; kb++) {
            half8 b0 = *reinterpret_cast<const half8*>(hbt + (0 + r) * 256 + kb * 32 + kg * 8);
            half8 b1 = *reinterpret_cast<const half8*>(hbt + (16 + r) * 256 + kb * 32 + kg * 8);
            q00 = MFMA16(ga0[kb], b0, q00);
            q01 = MFMA16(ga0[kb], b1, q01);
            q10 = MFMA16(ga1[kb], b0, q10);
            q11 = MFMA16(ga1[kb], b1, q11);
        }
        float bb0 = hbb[r], bb1 = hbb[16 + r];
#pragma unroll
        for (int i = 0; i < 4; i++) {
            q00[i] += bb0; q01[i] += bb1; q10[i] += bb0; q11[i] += bb1;
        }
    }

    for (int h = hbase; h < hbase + 64; h++) {
        float wb0 = hwb[h * 32 + r], wb1 = hwb[h * 32 + 16 + r];
        f32x4 w00 = {wb0, wb0, wb0, wb0};
        f32x4 w01 = {wb1, wb1, wb1, wb1};
        f32x4 w10 = w00, w11 = w01;
#pragma unroll
        for (int kb = 0; kb < 8; kb++) {
            half8 b0 = *reinterpret_cast<const half8*>(hwt + (h * 32 + 0 + r) * 256 + kb * 32 + kg * 8);
            half8 b1 = *reinterpret_cast<const half8*>(hwt + (h * 32 + 16 + r) * 256 + kb * 32 + kg * 8);
            w00 = MFMA16(ga0[kb], b0, w00);
            w01 = MFMA16(ga0[kb], b1, w01);
            w10 = MFMA16(ga1[kb], b0, w10);
            w11 = MFMA16(ga1[kb], b1, w11);
        }
#pragma unroll
        for (int i = 0; i < 4; i++) {
            float h0 = hnf[(row0 + kg * 4 + i) * 256 + h];
            float h1 = hnf[(row0 + 16 + kg * 4 + i) * 256 + h];
            q00[i] += h0 * w00[i];
            q01[i] += h0 * w01[i];
            q10[i] += h1 * w10[i];
            q11[i] += h1 * w11[i];
        }
    }

#pragma unroll
    for (int i = 0; i < 4; i++) {
        atomicAdd(&q[(row0 + kg * 4 + i) * 32 + r], q00[i]);
        atomicAdd(&q[(row0 + kg * 4 + i) * 32 + 16 + r], q01[i]);
        atomicAdd(&q[(row0 + 16 + kg * 4 + i) * 32 + r], q10[i]);
        atomicAdd(&q[(row0 + 16 + kg * 4 + i) * 32 + 16 + r], q11[i]);
    }
}

// ---------------------------------------------------------------------------
extern "C" void kernel_launch(void* const* d_in, const int* in_sizes, int n_in,
                              void* d_out, int out_size, void* d_ws, size_t ws_size,
                              hipStream_t stream) {
    const float* x = (const float*)d_in[0];
    const float* h = (const float*)d_in[1];
    const float* fc1_w = (const float*)d_in[2];
    const float* fc1_b = (const float*)d_in[3];
    const float* gwih = (const float*)d_in[4];
    const float* gbih = (const float*)d_in[5];
    const float* gwhh = (const float*)d_in[6];
    const float* gbhh = (const float*)d_in[7];
    const float* hgw1 = (const float*)d_in[8];
    const float* hgb1 = (const float*)d_in[9];
    const float* hgw2 = (const float*)d_in[10];
    const float* hgb2 = (const float*)d_in[11];
    const float* hbw = (const float*)d_in[12];
    const float* hbb = (const float*)d_in[13];
    const float* hww = (const float*)d_in[14];
    const float* hwb = (const float*)d_in[15];
    float* q = (float*)d_out;

    // workspace carve-up (f16 unless noted); total ~70 MB
    char* p = (char*)d_ws;
    auto alloc = [&](size_t bytes) { char* r = p; p += (bytes + 255) & ~255ULL; return r; };
    _Float16* x16 = (_Float16*)alloc((size_t)NROWS * DIM * 2);
    _Float16* h16 = (_Float16*)alloc((size_t)NROWS * DIM * 2);
    _Float16* w1t = (_Float16*)alloc((size_t)DIM * DIM * 2);
    _Float16* wiht = (_Float16*)alloc((size_t)3 * DIM * DIM * 2);
    _Float16* whht = (_Float16*)alloc((size_t)3 * DIM * DIM * 2);
    _Float16* hg1t = (_Float16*)alloc((size_t)DIM * DIM * 2);
    _Float16* hg2t = (_Float16*)alloc((size_t)DIM * DIM * 2);
    _Float16* hbt = (_Float16*)alloc((size_t)NACT * DIM * 2);
    _Float16* hwt = (_Float16*)alloc((size_t)DIM * NACT * DIM * 2);  // [8192][256]
    _Float16* x1 = (_Float16*)alloc((size_t)NROWS * DIM * 2);
    _Float16* hn16 = (_Float16*)alloc((size_t)NROWS * DIM * 2);
    float* hnf = (float*)alloc((size_t)NROWS * DIM * 4);
    _Float16* t16 = (_Float16*)alloc((size_t)NROWS * DIM * 2);
    _Float16* g16 = (_Float16*)alloc((size_t)NROWS * DIM * 2);

    // ---- prep ----
    {
        int n = NROWS * DIM;
        cvt_kernel<<<n / 4 / 256, 256, 0, stream>>>(x, x16, n);
        cvt_kernel<<<n / 4 / 256, 256, 0, stream>>>(h, h16, n);
        dim3 tb(32, 8);
        transpose_kernel<<<dim3(8, 8), tb, 0, stream>>>(fc1_w, w1t, 256, 256);
        transpose_kernel<<<dim3(8, 24), tb, 0, stream>>>(gwih, wiht, 256, 768);
        transpose_kernel<<<dim3(8, 24), tb, 0, stream>>>(gwhh, whht, 256, 768);
        transpose_kernel<<<dim3(8, 8), tb, 0, stream>>>(hgw1, hg1t, 256, 256);
        transpose_kernel<<<dim3(8, 8), tb, 0, stream>>>(hgw2, hg2t, 256, 256);
        transpose_kernel<<<dim3(8, 1), tb, 0, stream>>>(hbw, hbt, 256, 32);
        transpose_kernel<<<dim3(8, 256), tb, 0, stream>>>(hww, hwt, 256, 8192);
    }

    hipMemsetAsync(d_out, 0, (size_t)NROWS * NACT * sizeof(float), stream);

    // ---- stage 1: x1 = relu(x @ fc1_w + b) ----
    gemm_act_kernel<1><<<dim3(NROWS / 64, 4), 256, 0, stream>>>(x16, w1t, fc1_b, x1, DIM);

    // ---- stage 2: GRU ----
    gru_kernel<<<dim3(NROWS / 64, 2), 256, 0, stream>>>(x1, h16, h, wiht, whht, gbih, gbhh,
                                                        hn16, hnf);

    // ---- stage 3/4: hypernet latent ----
    gemm_act_kernel<1><<<dim3(NROWS / 64, 4), 256, 0, stream>>>(hn16, hg1t, hgb1, t16, DIM);
    gemm_act_kernel<2><<<dim3(NROWS / 64, 4), 256, 0, stream>>>(t16, hg2t, hgb2, g16, DIM);

    // ---- stage 5: fused b_dyn + w_dyn einsum ----
    final_kernel<<<dim3(NROWS / 128, 4), 256, 0, stream>>>(g16, hwt, hwb, hbt, hbb, hnf, q);
}

// Round 2
// 240.276 us; speedup vs baseline: 1.8476x; 1.8476x over previous
//
#include <hip/hip_runtime.h>

// ---------------------------------------------------------------------------
// GroupAgent fused pipeline v2, MI355X (gfx950), fp16 MFMA + f32 accumulate.
//   1. x1 = relu(x @ fc1_w + b)           -> xh[:, 0:256]
//   2. GRU (r,z via concat-K=512 GEMM)    -> hn16 [N][256], hnT f32 [256][N]
//   3. t = relu(hn @ hg_w1 + b)
//   4. g = tanh(t @ hg_w2 + b)
//   5. q = b_dyn + sum_h hn[:,h] * (g @ hw_w[:,h,:] + hw_b)   (LDS-staged B)
// hwt stored pre-swizzled (e ^= (a&7)<<3 per 16B group) so linear
// global_load_lds + swizzled ds_read_b128 is bank-conflict-free.
// ---------------------------------------------------------------------------

typedef _Float16 half8 __attribute__((ext_vector_type(8)));
typedef float f32x4 __attribute__((ext_vector_type(4)));

#define MFMA16(a, b, c) __builtin_amdgcn_mfma_f32_16x16x32_f16((a), (b), (c), 0, 0, 0)

constexpr int NROWS = 16384;

__device__ __forceinline__ float sigmoidf_(float x) { return 1.0f / (1.0f + __expf(-x)); }

__device__ __forceinline__ void glds16(const _Float16* g, _Float16* l) {
    __builtin_amdgcn_global_load_lds((const __attribute__((address_space(1))) void*)g,
                                     (__attribute__((address_space(3))) void*)l, 16, 0, 0);
}

// ---------------- prep: f32 -> f16 elementwise ----------------
__global__ void cvt_kernel(const float* __restrict__ in, _Float16* __restrict__ out, int n) {
    int i = (blockIdx.x * blockDim.x + threadIdx.x) * 4;
    if (i < n) {
        float4 v = *reinterpret_cast<const float4*>(in + i);
        out[i + 0] = (_Float16)v.x;
        out[i + 1] = (_Float16)v.y;
        out[i + 2] = (_Float16)v.z;
        out[i + 3] = (_Float16)v.w;
    }
}

// h f32 [N][256] -> xh[:, 256:512] f16 (row stride 512)
__global__ void cvt_h_kernel(const float* __restrict__ h, _Float16* __restrict__ xh) {
    int i = (blockIdx.x * blockDim.x + threadIdx.x) * 4;
    float4 v = *reinterpret_cast<const float4*>(h + i);
    int n = i >> 8, j = i & 255;
    _Float16* o = xh + n * 512 + 256 + j;
    o[0] = (_Float16)v.x; o[1] = (_Float16)v.y; o[2] = (_Float16)v.z; o[3] = (_Float16)v.w;
}

// ---------------- prep: transpose f32 [K][C] -> f16 [C][K] ----------------
// SWZ=true: hw_w path, writes out[h*8192 + a*256 + (k ^ ((a&7)<<3))], c = h*32+a.
template <bool SWZ>
__global__ void transpose_kernel(const float* __restrict__ in, _Float16* __restrict__ out,
                                 int in_rs, int out_rs) {
    __shared__ float tile[32][33];
    int kb = blockIdx.x * 32, cb = blockIdx.y * 32;
    int tx = threadIdx.x, ty = threadIdx.y;  // 32 x 8
#pragma unroll
    for (int i = ty; i < 32; i += 8) tile[i][tx] = in[(kb + i) * in_rs + (cb + tx)];
    __syncthreads();
#pragma unroll
    for (int i = ty; i < 32; i += 8) {
        int c = cb + i, k = kb + tx;
        if (SWZ) {
            int hh = c >> 5, a = c & 31;
            out[hh * 8192 + a * 256 + (k ^ ((a & 7) << 3))] = (_Float16)tile[tx][i];
        } else {
            out[c * out_rs + k] = (_Float16)tile[tx][i];
        }
    }
}

// ---------------- GEMM + bias + activation, 4 row-tiles/wave ----------------
// out[M][*] = act(A[M][256] @ W + bias); Wt is [C][256]. grid (M/256, C/64).
template <int ACT>  // 0 none, 1 relu, 2 tanh
__global__ __launch_bounds__(256, 2) void gemm_kernel(
    const _Float16* __restrict__ Am, const _Float16* __restrict__ Wt,
    const float* __restrict__ bias, _Float16* __restrict__ out16, int ONC) {
    const int tid = threadIdx.x, wave = tid >> 6, lane = tid & 63;
    const int r = lane & 15, kg = lane >> 4;
    const int row0 = blockIdx.x * 256 + wave * 64;
    const int col0 = blockIdx.y * 64;
    f32x4 z = {0.f, 0.f, 0.f, 0.f};
    f32x4 acc[4][4];
#pragma unroll
    for (int t = 0; t < 4; t++)
#pragma unroll
        for (int j = 0; j < 4; j++) acc[t][j] = z;
#pragma unroll
    for (int kb = 0; kb < 8; kb++) {
        half8 a[4], bm[4];
#pragma unroll
        for (int t = 0; t < 4; t++)
            a[t] = *reinterpret_cast<const half8*>(Am + (row0 + t * 16 + r) * 256 + kb * 32 + kg * 8);
#pragma unroll
        for (int j = 0; j < 4; j++)
            bm[j] = *reinterpret_cast<const half8*>(Wt + (col0 + j * 16 + r) * 256 + kb * 32 + kg * 8);
#pragma unroll
        for (int t = 0; t < 4; t++)
#pragma unroll
            for (int j = 0; j < 4; j++) acc[t][j] = MFMA16(a[t], bm[j], acc[t][j]);
    }
#pragma unroll
    for (int j = 0; j < 4; j++) {
        int cc = col0 + j * 16 + r;
        float bv = bias[cc];
#pragma unroll
        for (int t = 0; t < 4; t++)
#pragma unroll
            for (int i = 0; i < 4; i++) {
                int rr = row0 + t * 16 + kg * 4 + i;
                float v = acc[t][j][i] + bv;
                if (ACT == 1) v = fmaxf(v, 0.0f);
                if (ACT == 2) v = tanhf(v);
                out16[rr * ONC + cc] = (_Float16)v;
            }
    }
}

// ---------------- fused GRU cell ----------------
// r,z: K=512 GEMM over xh=[x1|h] vs wrzt[512][512] (cols: r 0-255, z 256-511)
// n:   i_n over xh[:,0:256] vs wnt rows 0-255; h_n over xh[:,256:512] vs wnt rows 256-511
// grid (64, 8): by covers 2 col-chunks of 16.
__global__ __launch_bounds__(256, 2) void gru_kernel(
    const _Float16* __restrict__ xh, const float* __restrict__ hf,
    const _Float16* __restrict__ wrzt, const _Float16* __restrict__ wnt,
    const float* __restrict__ bih, const float* __restrict__ bhh,
    _Float16* __restrict__ hn16, float* __restrict__ hnT) {
    const int tid = threadIdx.x, wave = tid >> 6, lane = tid & 63;
    const int r = lane & 15, kg = lane >> 4;
    const int row0 = blockIdx.x * 256 + wave * 64;
    for (int ci = 0; ci < 2; ++ci) {
        const int cc = (blockIdx.y * 2 + ci) * 16 + r;
        f32x4 z = {0.f, 0.f, 0.f, 0.f};
        f32x4 ar[4], az[4], ain[4], ahn[4];
#pragma unroll
        for (int t = 0; t < 4; t++) { ar[t] = z; az[t] = z; ain[t] = z; ahn[t] = z; }
#pragma unroll
        for (int kb = 0; kb < 16; ++kb) {
            half8 a[4];
#pragma unroll
            for (int t = 0; t < 4; t++)
                a[t] = *reinterpret_cast<const half8*>(xh + (row0 + t * 16 + r) * 512 + kb * 32 + kg * 8);
            half8 br = *reinterpret_cast<const half8*>(wrzt + cc * 512 + kb * 32 + kg * 8);
            half8 bz = *reinterpret_cast<const half8*>(wrzt + (256 + cc) * 512 + kb * 32 + kg * 8);
            half8 bn = (kb < 8)
                ? *reinterpret_cast<const half8*>(wnt + cc * 256 + kb * 32 + kg * 8)
                : *reinterpret_cast<const half8*>(wnt + (256 + cc) * 256 + (kb - 8) * 32 + kg * 8);
#pragma unroll
            for (int t = 0; t < 4; t++) {
                ar[t] = MFMA16(a[t], br, ar[t]);
                az[t] = MFMA16(a[t], bz, az[t]);
            }
            if (kb < 8) {
#pragma unroll
                for (int t = 0; t < 4; t++) ain[t] = MFMA16(a[t], bn, ain[t]);
            } else {
#pragma unroll
                for (int t = 0; t < 4; t++) ahn[t] = MFMA16(a[t], bn, ahn[t]);
            }
        }
        float brz = bih[cc] + bhh[cc];
        float bzz = bih[256 + cc] + bhh[256 + cc];
        float bin = bih[512 + cc], bhn = bhh[512 + cc];
#pragma unroll
        for (int t = 0; t < 4; t++)
#pragma unroll
            for (int i = 0; i < 4; i++) {
                int rr = row0 + t * 16 + kg * 4 + i;
                float hval = hf[rr * 256 + cc];
                float rg = sigmoidf_(ar[t][i] + brz);
                float zg = sigmoidf_(az[t][i] + bzz);
                float nn = tanhf(ain[t][i] + bin + rg * (ahn[t][i] + bhn));
                float v = (1.0f - zg) * nn + zg * hval;
                hn16[rr * 256 + cc] = (_Float16)v;
                hnT[cc * 16384 + rr] = v;
            }
    }
}

// ---------------- fused final stage ----------------
// Wave = 64 rows x 32 actions; block 4 waves = 256 rows; grid (64, 8).
// A (g) hoisted full-K in regs; B (hwt, pre-swizzled) LDS double-buffered,
// 2 h per chunk (32KB); hn read as f32 from hnT. atomicAdd to zeroed q.
__global__ __launch_bounds__(256, 2) void final_kernel(
    const _Float16* __restrict__ g16, const _Float16* __restrict__ hwt,
    const float* __restrict__ hwb, const _Float16* __restrict__ hbt,
    const float* __restrict__ hbb, const float* __restrict__ hnT,
    float* __restrict__ q) {
    __shared__ _Float16 Bs[2][16384];  // [buf][2 h-tiles of 8192 f16]
    __shared__ float hwbs[1024];       // 32 h x 32 a slice of hw_b
    const int tid = threadIdx.x, wave = tid >> 6, lane = tid & 63;
    const int r = lane & 15, kg = lane >> 4;
    const int row0 = blockIdx.x * 256 + wave * 64;
    const int hbase = blockIdx.y * 32;

    // hoist g fragments: 4 row-tiles x full K=256
    half8 ga[4][8];
#pragma unroll
    for (int t = 0; t < 4; t++)
#pragma unroll
        for (int kb = 0; kb < 8; kb++)
            ga[t][kb] = *reinterpret_cast<const half8*>(g16 + (row0 + t * 16 + r) * 256 + kb * 32 + kg * 8);

    // stage chunk 0 + hwb slice (overlaps the b_dyn work below)
    {
        const _Float16* src = hwt + (size_t)hbase * 8192;
#pragma unroll
        for (int it = 0; it < 8; ++it)
            glds16(src + it * 2048 + tid * 8, &Bs[0][0] + it * 2048 + tid * 8);
        *reinterpret_cast<float4*>(&hwbs[tid * 4]) =
            *reinterpret_cast<const float4*>(hwb + hbase * 32 + tid * 4);
    }

    f32x4 qa[4][2];
    if (blockIdx.y == 0) {  // fuse b_dyn = g @ hb_w + hb_b
        float b0v = hbb[r], b1v = hbb[16 + r];
#pragma unroll
        for (int t = 0; t < 4; t++) {
            qa[t][0] = {b0v, b0v, b0v, b0v};
            qa[t][1] = {b1v, b1v, b1v, b1v};
        }
#pragma unroll
        for (int kb = 0; kb < 8; kb++) {
            half8 hb0 = *reinterpret_cast<const half8*>(hbt + r * 256 + kb * 32 + kg * 8);
            half8 hb1 = *reinterpret_cast<const half8*>(hbt + (16 + r) * 256 + kb * 32 + kg * 8);
#pragma unroll
            for (int t = 0; t < 4; t++) {
                qa[t][0] = MFMA16(ga[t][kb], hb0, qa[t][0]);
                qa[t][1] = MFMA16(ga[t][kb], hb1, qa[t][1]);
            }
        }
    } else {
        f32x4 z = {0.f, 0.f, 0.f, 0.f};
#pragma unroll
        for (int t = 0; t < 4; t++) { qa[t][0] = z; qa[t][1] = z; }
    }

    asm volatile("s_waitcnt vmcnt(0)");
    __syncthreads();

    const int swz = (r & 7) << 4;
    for (int c = 0; c < 16; ++c) {
        const int b = c & 1;
        if (c < 15) {  // prefetch next 2-h chunk into other buffer
            const _Float16* src = hwt + (size_t)(hbase + (c + 1) * 2) * 8192;
            _Float16* dst = &Bs[b ^ 1][0];
#pragma unroll
            for (int it = 0; it < 8; ++it)
                glds16(src + it * 2048 + tid * 8, dst + it * 2048 + tid * 8);
        }
#pragma unroll
        for (int hh = 0; hh < 2; ++hh) {
            const int hloc = c * 2 + hh;
            const int h = hbase + hloc;
            const char* bp = (const char*)&Bs[b][hh * 8192];
            float wb0 = hwbs[hloc * 32 + r], wb1 = hwbs[hloc * 32 + 16 + r];
            f32x4 w[4][2];
#pragma unroll
            for (int t = 0; t < 4; t++) {
                w[t][0] = {wb0, wb0, wb0, wb0};
                w[t][1] = {wb1, wb1, wb1, wb1};
            }
#pragma unroll
            for (int kb = 0; kb < 8; kb++) {
                const int c0 = kb * 64 + kg * 16;
                half8 b0 = *reinterpret_cast<const half8*>(bp + r * 512 + (c0 ^ swz));
                half8 b1 = *reinterpret_cast<const half8*>(bp + (16 + r) * 512 + (c0 ^ swz));
#pragma unroll
                for (int t = 0; t < 4; t++) {
                    w[t][0] = MFMA16(ga[t][kb], b0, w[t][0]);
                    w[t][1] = MFMA16(ga[t][kb], b1, w[t][1]);
                }
            }
#pragma unroll
            for (int t = 0; t < 4; t++) {
                f32x4 hv = *reinterpret_cast<const f32x4*>(hnT + h * 16384 + row0 + t * 16 + kg * 4);
#pragma unroll
                for (int i = 0; i < 4; i++) {
                    qa[t][0][i] += hv[i] * w[t][0][i];
                    qa[t][1][i] += hv[i] * w[t][1][i];
                }
            }
        }
        asm volatile("s_waitcnt vmcnt(0)");
        __syncthreads();
    }

#pragma unroll
    for (int t = 0; t < 4; t++)
#pragma unroll
        for (int i = 0; i < 4; i++) {
            int rr = row0 + t * 16 + kg * 4 + i;
            atomicAdd(&q[rr * 32 + r], qa[t][0][i]);
            atomicAdd(&q[rr * 32 + 16 + r], qa[t][1][i]);
        }
}

// ---------------------------------------------------------------------------
extern "C" void kernel_launch(void* const* d_in, const int* in_sizes, int n_in,
                              void* d_out, int out_size, void* d_ws, size_t ws_size,
                              hipStream_t stream) {
    const float* x = (const float*)d_in[0];
    const float* h = (const float*)d_in[1];
    const float* fc1_w = (const float*)d_in[2];
    const float* fc1_b = (const float*)d_in[3];
    const float* gwih = (const float*)d_in[4];
    const float* gbih = (const float*)d_in[5];
    const float* gwhh = (const float*)d_in[6];
    const float* gbhh = (const float*)d_in[7];
    const float* hgw1 = (const float*)d_in[8];
    const float* hgb1 = (const float*)d_in[9];
    const float* hgw2 = (const float*)d_in[10];
    const float* hgb2 = (const float*)d_in[11];
    const float* hbw = (const float*)d_in[12];
    const float* hbb = (const float*)d_in[13];
    const float* hww = (const float*)d_in[14];
    const float* hwb = (const float*)d_in[15];
    float* q = (float*)d_out;

    char* p = (char*)d_ws;
    auto alloc = [&](size_t bytes) { char* r = p; p += (bytes + 255) & ~255ULL; return r; };
    _Float16* x16 = (_Float16*)alloc((size_t)NROWS * 256 * 2);
    _Float16* xh = (_Float16*)alloc((size_t)NROWS * 512 * 2);
    _Float16* w1t = (_Float16*)alloc((size_t)256 * 256 * 2);
    _Float16* wrzt = (_Float16*)alloc((size_t)512 * 512 * 2);
    _Float16* wnt = (_Float16*)alloc((size_t)512 * 256 * 2);
    _Float16* hg1t = (_Float16*)alloc((size_t)256 * 256 * 2);
    _Float16* hg2t = (_Float16*)alloc((size_t)256 * 256 * 2);
    _Float16* hbt = (_Float16*)alloc((size_t)32 * 256 * 2);
    _Float16* hwt = (_Float16*)alloc((size_t)256 * 8192 * 2);  // swizzled [h][a][e^]
    _Float16* hn16 = (_Float16*)alloc((size_t)NROWS * 256 * 2);
    float* hnT = (float*)alloc((size_t)256 * NROWS * 4);
    _Float16* t16 = (_Float16*)alloc((size_t)NROWS * 256 * 2);
    _Float16* g16 = (_Float16*)alloc((size_t)NROWS * 256 * 2);

    // ---- prep ----
    {
        int n = NROWS * 256;
        cvt_kernel<<<n / 4 / 256, 256, 0, stream>>>(x, x16, n);
        cvt_h_kernel<<<n / 4 / 256, 256, 0, stream>>>(h, xh);
        dim3 tb(32, 8);
        transpose_kernel<false><<<dim3(8, 8), tb, 0, stream>>>(fc1_w, w1t, 256, 256);
        // GRU weights: wrzt [512 cols(r|z)][512 k(ih|hh)], wnt [512 rows(i_n|h_n)][256]
        transpose_kernel<false><<<dim3(8, 8), tb, 0, stream>>>(gwih + 0, wrzt + 0, 768, 512);
        transpose_kernel<false><<<dim3(8, 8), tb, 0, stream>>>(gwhh + 0, wrzt + 256, 768, 512);
        transpose_kernel<false><<<dim3(8, 8), tb, 0, stream>>>(gwih + 256, wrzt + 256 * 512, 768, 512);
        transpose_kernel<false><<<dim3(8, 8), tb, 0, stream>>>(gwhh + 256, wrzt + 256 * 512 + 256, 768, 512);
        transpose_kernel<false><<<dim3(8, 8), tb, 0, stream>>>(gwih + 512, wnt, 768, 256);
        transpose_kernel<false><<<dim3(8, 8), tb, 0, stream>>>(gwhh + 512, wnt + 256 * 256, 768, 256);
        transpose_kernel<false><<<dim3(8, 8), tb, 0, stream>>>(hgw1, hg1t, 256, 256);
        transpose_kernel<false><<<dim3(8, 8), tb, 0, stream>>>(hgw2, hg2t, 256, 256);
        transpose_kernel<false><<<dim3(8, 1), tb, 0, stream>>>(hbw, hbt, 32, 256);
        transpose_kernel<true><<<dim3(8, 256), tb, 0, stream>>>(hww, hwt, 8192, 0);
    }

    hipMemsetAsync(d_out, 0, (size_t)NROWS * 32 * sizeof(float), stream);

    // ---- stage 1: x1 = relu(x @ fc1_w + b) -> xh[:, 0:256] ----
    gemm_kernel<1><<<dim3(NROWS / 256, 4), 256, 0, stream>>>(x16, w1t, fc1_b, xh, 512);

    // ---- stage 2: GRU ----
    gru_kernel<<<dim3(NROWS / 256, 8), 256, 0, stream>>>(xh, h, wrzt, wnt, gbih, gbhh,
                                                         hn16, hnT);

    // ---- stage 3/4: hypernet latent ----
    gemm_kernel<1><<<dim3(NROWS / 256, 4), 256, 0, stream>>>(hn16, hg1t, hgb1, t16, 256);
    gemm_kernel<2><<<dim3(NROWS / 256, 4), 256, 0, stream>>>(t16, hg2t, hgb2, g16, 256);

    // ---- stage 5: fused b_dyn + w_dyn einsum ----
    final_kernel<<<dim3(NROWS / 256, 8), 256, 0, stream>>>(g16, hwt, hwb, hbt, hbb, hnT, q);
}

// Round 3
// 188.714 us; speedup vs baseline: 2.3525x; 1.2732x over previous
//
#include <hip/hip_runtime.h>

// ---------------------------------------------------------------------------
// GroupAgent fused pipeline v3, MI355X (gfx950), fp16 MFMA + f32 accumulate.
//   1. x1 = relu(x @ fc1_w + b)           -> xh[:, 0:256]   (LDS-staged B)
//   2. GRU as ONE interleaved-gate GEMM [N,512]@[512,1024] + fused gates
//   3. t = relu(hn @ hg_w1 + b)            (LDS-staged B)
//   4. g = tanh(t @ hg_w2 + b)             (LDS-staged B)
//   5. q = b_dyn + sum_h hn[:,h] * (g @ hw_w[:,h,:] + hw_b)  (ga reg-pinned)
// All weights pre-transposed to f16 [col][K] with XOR swizzle
// (k ^ ((col&7)<<3) on 8-elem groups) so linear global_load_lds +
// swizzled ds_read_b128 is bank-conflict-free.
// hn transposed to f32 hnT[256][16384] by a coalesced tile-transpose kernel.
// ---------------------------------------------------------------------------

typedef _Float16 half8 __attribute__((ext_vector_type(8)));
typedef float f32x4 __attribute__((ext_vector_type(4)));

#define MFMA16(a, b, c) __builtin_amdgcn_mfma_f32_16x16x32_f16((a), (b), (c), 0, 0, 0)

constexpr int NROWS = 16384;

__device__ __forceinline__ float sigmoidf_(float x) { return 1.0f / (1.0f + __expf(-x)); }

__device__ __forceinline__ void glds16(const _Float16* g, _Float16* l) {
    __builtin_amdgcn_global_load_lds((const __attribute__((address_space(1))) void*)g,
                                     (__attribute__((address_space(3))) void*)l, 16, 0, 0);
}

// ---------------- prep: x -> x16, h -> xh[:,256:512] ----------------
__global__ void cvt_kernel(const float* __restrict__ x, const float* __restrict__ h,
                           _Float16* __restrict__ x16, _Float16* __restrict__ xh) {
    int b = blockIdx.x;
    if (b < 4096) {
        int i = (b * 256 + threadIdx.x) * 4;
        float4 v = *reinterpret_cast<const float4*>(x + i);
        x16[i + 0] = (_Float16)v.x; x16[i + 1] = (_Float16)v.y;
        x16[i + 2] = (_Float16)v.z; x16[i + 3] = (_Float16)v.w;
    } else {
        int i = ((b - 4096) * 256 + threadIdx.x) * 4;
        float4 v = *reinterpret_cast<const float4*>(h + i);
        int n = i >> 8, j = i & 255;
        _Float16* o = xh + n * 512 + 256 + j;
        o[0] = (_Float16)v.x; o[1] = (_Float16)v.y;
        o[2] = (_Float16)v.z; o[3] = (_Float16)v.w;
    }
}

// ---------------- prep: unified weight transpose+swizzle ----------------
// in[k][C] f32 -> out[c*256 + (k ^ ((c&7)<<3))] f16.  K=256 for all segments.
// tiles of 32k x 32c; segments: fc1(64) hg1(64) hg2(64) hbw(8) hww(2048).
__global__ void wtrans_kernel(const float* __restrict__ s0, const float* __restrict__ s1,
                              const float* __restrict__ s2, const float* __restrict__ s3,
                              const float* __restrict__ s4, _Float16* __restrict__ d0,
                              _Float16* __restrict__ d1, _Float16* __restrict__ d2,
                              _Float16* __restrict__ d3, _Float16* __restrict__ d4) {
    __shared__ float tile[32][33];
    int b = blockIdx.x;
    const float* src; _Float16* dst; int C, idx;
    if (b < 64)       { src = s0; dst = d0; C = 256;  idx = b; }
    else if (b < 128) { src = s1; dst = d1; C = 256;  idx = b - 64; }
    else if (b < 192) { src = s2; dst = d2; C = 256;  idx = b - 128; }
    else if (b < 200) { src = s3; dst = d3; C = 32;   idx = b - 192; }
    else              { src = s4; dst = d4; C = 8192; idx = b - 200; }
    int kb = (idx & 7) * 32, cb = (idx >> 3) * 32;
    int tx = threadIdx.x, ty = threadIdx.y;  // 32 x 8
#pragma unroll
    for (int i = ty; i < 32; i += 8) tile[i][tx] = src[(kb + i) * C + cb + tx];
    __syncthreads();
#pragma unroll
    for (int i = ty; i < 32; i += 8) {
        int c = cb + i, k = kb + tx;
        dst[c * 256 + (k ^ ((c & 7) << 3))] = (_Float16)tile[tx][i];
    }
}

// ---------------- prep: GRU interleaved-gate weight pack ----------------
// wgru[1024][512] f16 swizzled. row = cg*64 + gate*16 + rr, col c = cg*16+rr.
// gate 0(r)/1(z): k<256 -> gwih[k][g*256+c], else gwhh[k-256][g*256+c]
// gate 2(i_n):    k<256 -> gwih[k][512+c], else 0
// gate 3(h_n):    k<256 -> 0, else gwhh[k-256][512+c]
__global__ void wgru_prep_kernel(const float* __restrict__ gwih, const float* __restrict__ gwhh,
                                 _Float16* __restrict__ wgru) {
    int t = blockIdx.x * 256 + threadIdx.x;  // 64K threads, 8 elems each
    int row = t >> 6, k0 = (t & 63) << 3;
    int gate = (row >> 4) & 3, c = (row >> 6) * 16 + (row & 15);
    half8 v;
#pragma unroll
    for (int e = 0; e < 8; e++) {
        int k = k0 + e;
        float f;
        if (gate == 0) f = (k < 256) ? gwih[k * 768 + c] : gwhh[(k - 256) * 768 + c];
        else if (gate == 1) f = (k < 256) ? gwih[k * 768 + 256 + c] : gwhh[(k - 256) * 768 + 256 + c];
        else if (gate == 2) f = (k < 256) ? gwih[k * 768 + 512 + c] : 0.0f;
        else f = (k < 256) ? 0.0f : gwhh[(k - 256) * 768 + 512 + c];
        v[e] = (_Float16)f;
    }
    *reinterpret_cast<half8*>(wgru + row * 512 + (k0 ^ ((row & 7) << 3))) = v;
}

// ---------------- GEMM + bias + activation, LDS-staged B ----------------
// out[M][ONC] = act(A[M][256] @ W + bias); Wt swizzled [C][256].
// grid (64, C/64), block 256 = 4 waves x 64 rows.
template <int ACT>  // 1 relu, 2 tanh
__global__ __launch_bounds__(256, 2) void gemm_lds_kernel(
    const _Float16* __restrict__ Am, const _Float16* __restrict__ Wt,
    const float* __restrict__ bias, _Float16* __restrict__ out16, int ONC) {
    __shared__ _Float16 Bs[64 * 256];  // 32 KB
    const int tid = threadIdx.x, wave = tid >> 6, lane = tid & 63;
    const int r = lane & 15, kg = lane >> 4;
    const int row0 = blockIdx.x * 256 + wave * 64;
    const int col0 = blockIdx.y * 64;
    const _Float16* src = Wt + col0 * 256;
#pragma unroll
    for (int it = 0; it < 8; ++it)
        glds16(src + it * 2048 + tid * 8, Bs + it * 2048 + tid * 8);
    asm volatile("s_waitcnt vmcnt(0)");
    __syncthreads();

    f32x4 z = {0.f, 0.f, 0.f, 0.f};
    f32x4 acc[4][4];
#pragma unroll
    for (int t = 0; t < 4; t++)
#pragma unroll
        for (int j = 0; j < 4; j++) acc[t][j] = z;
    const int swz = (r & 7) << 4;
#pragma unroll
    for (int kb = 0; kb < 8; kb++) {
        half8 a[4], bm[4];
#pragma unroll
        for (int t = 0; t < 4; t++)
            a[t] = *reinterpret_cast<const half8*>(Am + (row0 + t * 16 + r) * 256 + kb * 32 + kg * 8);
#pragma unroll
        for (int j = 0; j < 4; j++)
            bm[j] = *reinterpret_cast<const half8*>(
                (const char*)Bs + (j * 16 + r) * 512 + ((kb * 64 + kg * 16) ^ swz));
#pragma unroll
        for (int t = 0; t < 4; t++)
#pragma unroll
            for (int j = 0; j < 4; j++) acc[t][j] = MFMA16(a[t], bm[j], acc[t][j]);
    }
#pragma unroll
    for (int j = 0; j < 4; j++) {
        int cc = col0 + j * 16 + r;
        float bv = bias[cc];
#pragma unroll
        for (int t = 0; t < 4; t++)
#pragma unroll
            for (int i = 0; i < 4; i++) {
                int rr = row0 + t * 16 + kg * 4 + i;
                float v = acc[t][j][i] + bv;
                if (ACT == 1) v = fmaxf(v, 0.0f);
                if (ACT == 2) v = tanhf(v);
                out16[rr * ONC + cc] = (_Float16)v;
            }
    }
}

// ---------------- fused GRU: one GEMM + gate epilogue ----------------
// A = xh[N][512] = [x1|h16]; B-tile = wgru rows y*64..y*64+63 (gates r,z,in,hn
// for cols y*16..y*16+15), K=512, staged in LDS (64 KB). grid (64, 16).
__global__ __launch_bounds__(256, 2) void gru_kernel(
    const _Float16* __restrict__ xh, const float* __restrict__ hf,
    const _Float16* __restrict__ wgru, const float* __restrict__ bih,
    const float* __restrict__ bhh, _Float16* __restrict__ hn16) {
    __shared__ _Float16 Bs[64 * 512];  // 64 KB
    const int tid = threadIdx.x, wave = tid >> 6, lane = tid & 63;
    const int r = lane & 15, kg = lane >> 4;
    const int row0 = blockIdx.x * 256 + wave * 64;
    const int c0 = blockIdx.y * 16;
    const _Float16* src = wgru + (size_t)blockIdx.y * 64 * 512;
#pragma unroll
    for (int it = 0; it < 16; ++it)
        glds16(src + it * 2048 + tid * 8, Bs + it * 2048 + tid * 8);
    asm volatile("s_waitcnt vmcnt(0)");
    __syncthreads();

    f32x4 z = {0.f, 0.f, 0.f, 0.f};
    f32x4 acc[4][4];  // [row-tile][gate]
#pragma unroll
    for (int t = 0; t < 4; t++)
#pragma unroll
        for (int j = 0; j < 4; j++) acc[t][j] = z;
    const int swz = (r & 7) << 4;
#pragma unroll
    for (int kb = 0; kb < 16; kb++) {
        half8 a[4], bm[4];
#pragma unroll
        for (int t = 0; t < 4; t++)
            a[t] = *reinterpret_cast<const half8*>(xh + (row0 + t * 16 + r) * 512 + kb * 32 + kg * 8);
#pragma unroll
        for (int j = 0; j < 4; j++)
            bm[j] = *reinterpret_cast<const half8*>(
                (const char*)Bs + (j * 16 + r) * 1024 + ((kb * 64 + kg * 16) ^ swz));
#pragma unroll
        for (int t = 0; t < 4; t++)
#pragma unroll
            for (int j = 0; j < 4; j++) acc[t][j] = MFMA16(a[t], bm[j], acc[t][j]);
    }
    const int cc = c0 + r;
    float brz = bih[cc] + bhh[cc];
    float bzz = bih[256 + cc] + bhh[256 + cc];
    float bin = bih[512 + cc], bhn = bhh[512 + cc];
#pragma unroll
    for (int t = 0; t < 4; t++)
#pragma unroll
        for (int i = 0; i < 4; i++) {
            int rr = row0 + t * 16 + kg * 4 + i;
            float rg = sigmoidf_(acc[t][0][i] + brz);
            float zg = sigmoidf_(acc[t][1][i] + bzz);
            float nn = tanhf(acc[t][2][i] + bin + rg * (acc[t][3][i] + bhn));
            float v = (1.0f - zg) * nn + zg * hf[rr * 256 + cc];
            hn16[rr * 256 + cc] = (_Float16)v;
        }
}

// ---------------- hn16 [N][256] f16 -> hnT [256][N] f32, coalesced ----------------
__global__ void hnt_kernel(const _Float16* __restrict__ hn16, float* __restrict__ hnT) {
    __shared__ float tile[32][33];
    int r0 = blockIdx.x * 32, c0 = blockIdx.y * 32;
    int tx = threadIdx.x, ty = threadIdx.y;  // 32 x 8
#pragma unroll
    for (int i = ty; i < 32; i += 8) tile[i][tx] = (float)hn16[(r0 + i) * 256 + c0 + tx];
    __syncthreads();
#pragma unroll
    for (int i = ty; i < 32; i += 8) hnT[(size_t)(c0 + i) * NROWS + r0 + tx] = tile[tx][i];
}

// ---------------- fused final stage ----------------
// Wave = 64 rows x 32 actions; block = 256 rows; grid (64, 8), y -> 32-h slice.
// ga pinned in registers (asm) for the whole kernel; B LDS double-buffered.
__global__ __launch_bounds__(256, 2) void final_kernel(
    const _Float16* __restrict__ g16, const _Float16* __restrict__ hwt,
    const float* __restrict__ hwb, const _Float16* __restrict__ hbt,
    const float* __restrict__ hbb, const float* __restrict__ hnT,
    float* __restrict__ q) {
    __shared__ _Float16 Bs[2][16384];  // 2 x 32 KB (2 h per chunk)
    __shared__ float hwbs[1024];
    const int tid = threadIdx.x, wave = tid >> 6, lane = tid & 63;
    const int r = lane & 15, kg = lane >> 4;
    const int row0 = blockIdx.x * 256 + wave * 64;
    const int hbase = blockIdx.y * 32;
    const int swz = (r & 7) << 4;

    // hoist g fragments: 4 row-tiles x full K=256, pinned resident (128 VGPR)
    half8 ga[4][8];
#pragma unroll
    for (int t = 0; t < 4; t++)
#pragma unroll
        for (int kb = 0; kb < 8; kb++)
            ga[t][kb] = *reinterpret_cast<const half8*>(g16 + (row0 + t * 16 + r) * 256 + kb * 32 + kg * 8);
#pragma unroll
    for (int t = 0; t < 4; t++)
#pragma unroll
        for (int kb = 0; kb < 8; kb++)
            asm volatile("" : "+v"(ga[t][kb]));

    // stage chunk 0 + hwb slice
    {
        const _Float16* src = hwt + (size_t)hbase * 8192;
#pragma unroll
        for (int it = 0; it < 8; ++it)
            glds16(src + it * 2048 + tid * 8, &Bs[0][0] + it * 2048 + tid * 8);
        *reinterpret_cast<float4*>(&hwbs[tid * 4]) =
            *reinterpret_cast<const float4*>(hwb + hbase * 32 + tid * 4);
    }

    f32x4 qa[4][2];
    if (blockIdx.y == 0) {  // fuse b_dyn = g @ hb_w + hb_b (hbt is swizzled too)
        float b0v = hbb[r], b1v = hbb[16 + r];
#pragma unroll
        for (int t = 0; t < 4; t++) {
            qa[t][0] = {b0v, b0v, b0v, b0v};
            qa[t][1] = {b1v, b1v, b1v, b1v};
        }
#pragma unroll
        for (int kb = 0; kb < 8; kb++) {
            half8 hb0 = *reinterpret_cast<const half8*>(
                (const char*)hbt + r * 512 + ((kb * 64 + kg * 16) ^ swz));
            half8 hb1 = *reinterpret_cast<const half8*>(
                (const char*)hbt + (16 + r) * 512 + ((kb * 64 + kg * 16) ^ swz));
#pragma unroll
            for (int t = 0; t < 4; t++) {
                qa[t][0] = MFMA16(ga[t][kb], hb0, qa[t][0]);
                qa[t][1] = MFMA16(ga[t][kb], hb1, qa[t][1]);
            }
        }
    } else {
        f32x4 z = {0.f, 0.f, 0.f, 0.f};
#pragma unroll
        for (int t = 0; t < 4; t++) { qa[t][0] = z; qa[t][1] = z; }
    }

    asm volatile("s_waitcnt vmcnt(0)");
    __syncthreads();

    for (int c = 0; c < 16; ++c) {
        const int b = c & 1;
        if (c < 15) {  // prefetch next 2-h chunk into other buffer
            const _Float16* src = hwt + (size_t)(hbase + (c + 1) * 2) * 8192;
            _Float16* dst = &Bs[b ^ 1][0];
#pragma unroll
            for (int it = 0; it < 8; ++it)
                glds16(src + it * 2048 + tid * 8, dst + it * 2048 + tid * 8);
        }
#pragma unroll
        for (int hh = 0; hh < 2; ++hh) {
            const int hloc = c * 2 + hh;
            const int h = hbase + hloc;
            const char* bp = (const char*)&Bs[b][hh * 8192];
            float wb0 = hwbs[hloc * 32 + r], wb1 = hwbs[hloc * 32 + 16 + r];
            f32x4 w[4][2];
#pragma unroll
            for (int t = 0; t < 4; t++) {
                w[t][0] = {wb0, wb0, wb0, wb0};
                w[t][1] = {wb1, wb1, wb1, wb1};
            }
#pragma unroll
            for (int kb = 0; kb < 8; kb++) {
                const int c0b = (kb * 64 + kg * 16) ^ swz;
                half8 b0 = *reinterpret_cast<const half8*>(bp + r * 512 + c0b);
                half8 b1 = *reinterpret_cast<const half8*>(bp + (16 + r) * 512 + c0b);
#pragma unroll
                for (int t = 0; t < 4; t++) {
                    w[t][0] = MFMA16(ga[t][kb], b0, w[t][0]);
                    w[t][1] = MFMA16(ga[t][kb], b1, w[t][1]);
                }
            }
#pragma unroll
            for (int t = 0; t < 4; t++) {
                f32x4 hv = *reinterpret_cast<const f32x4*>(hnT + (size_t)h * NROWS + row0 + t * 16 + kg * 4);
#pragma unroll
                for (int i = 0; i < 4; i++) {
                    qa[t][0][i] += hv[i] * w[t][0][i];
                    qa[t][1][i] += hv[i] * w[t][1][i];
                }
            }
        }
        asm volatile("s_waitcnt vmcnt(0)");
        __syncthreads();
    }

#pragma unroll
    for (int t = 0; t < 4; t++)
#pragma unroll
        for (int i = 0; i < 4; i++) {
            int rr = row0 + t * 16 + kg * 4 + i;
            atomicAdd(&q[rr * 32 + r], qa[t][0][i]);
            atomicAdd(&q[rr * 32 + 16 + r], qa[t][1][i]);
        }
}

// ---------------------------------------------------------------------------
extern "C" void kernel_launch(void* const* d_in, const int* in_sizes, int n_in,
                              void* d_out, int out_size, void* d_ws, size_t ws_size,
                              hipStream_t stream) {
    const float* x = (const float*)d_in[0];
    const float* h = (const float*)d_in[1];
    const float* fc1_w = (const float*)d_in[2];
    const float* fc1_b = (const float*)d_in[3];
    const float* gwih = (const float*)d_in[4];
    const float* gbih = (const float*)d_in[5];
    const float* gwhh = (const float*)d_in[6];
    const float* gbhh = (const float*)d_in[7];
    const float* hgw1 = (const float*)d_in[8];
    const float* hgb1 = (const float*)d_in[9];
    const float* hgw2 = (const float*)d_in[10];
    const float* hgb2 = (const float*)d_in[11];
    const float* hbw = (const float*)d_in[12];
    const float* hbb = (const float*)d_in[13];
    const float* hww = (const float*)d_in[14];
    const float* hwb = (const float*)d_in[15];
    float* q = (float*)d_out;

    char* p = (char*)d_ws;
    auto alloc = [&](size_t bytes) { char* r = p; p += (bytes + 255) & ~255ULL; return r; };
    _Float16* x16 = (_Float16*)alloc((size_t)NROWS * 256 * 2);
    _Float16* xh = (_Float16*)alloc((size_t)NROWS * 512 * 2);
    _Float16* w1t = (_Float16*)alloc((size_t)256 * 256 * 2);
    _Float16* wgru = (_Float16*)alloc((size_t)1024 * 512 * 2);
    _Float16* hg1t = (_Float16*)alloc((size_t)256 * 256 * 2);
    _Float16* hg2t = (_Float16*)alloc((size_t)256 * 256 * 2);
    _Float16* hbt = (_Float16*)alloc((size_t)32 * 256 * 2);
    _Float16* hwt = (_Float16*)alloc((size_t)8192 * 256 * 2);
    _Float16* hn16 = (_Float16*)alloc((size_t)NROWS * 256 * 2);
    float* hnT = (float*)alloc((size_t)256 * NROWS * 4);
    _Float16* t16 = (_Float16*)alloc((size_t)NROWS * 256 * 2);
    _Float16* g16 = (_Float16*)alloc((size_t)NROWS * 256 * 2);

    // ---- prep (3 kernels) ----
    cvt_kernel<<<8192, 256, 0, stream>>>(x, h, x16, xh);
    wtrans_kernel<<<2248, dim3(32, 8), 0, stream>>>(fc1_w, hgw1, hgw2, hbw, hww,
                                                    w1t, hg1t, hg2t, hbt, hwt);
    wgru_prep_kernel<<<256, 256, 0, stream>>>(gwih, gwhh, wgru);

    hipMemsetAsync(d_out, 0, (size_t)NROWS * 32 * sizeof(float), stream);

    // ---- stage 1: x1 = relu(x @ fc1_w + b) -> xh[:, 0:256] ----
    gemm_lds_kernel<1><<<dim3(64, 4), 256, 0, stream>>>(x16, w1t, fc1_b, xh, 512);

    // ---- stage 2: GRU ----
    gru_kernel<<<dim3(64, 16), 256, 0, stream>>>(xh, h, wgru, gbih, gbhh, hn16);
    hnt_kernel<<<dim3(512, 8), dim3(32, 8), 0, stream>>>(hn16, hnT);

    // ---- stage 3/4: hypernet latent ----
    gemm_lds_kernel<1><<<dim3(64, 4), 256, 0, stream>>>(hn16, hg1t, hgb1, t16, 256);
    gemm_lds_kernel<2><<<dim3(64, 4), 256, 0, stream>>>(t16, hg2t, hgb2, g16, 256);

    // ---- stage 5: fused b_dyn + w_dyn einsum ----
    final_kernel<<<dim3(64, 8), 256, 0, stream>>>(g16, hwt, hwb, hbt, hbb, hnT, q);
}

// Round 4
// 185.127 us; speedup vs baseline: 2.3980x; 1.0194x over previous
//
#include <hip/hip_runtime.h>

// ---------------------------------------------------------------------------
// GroupAgent fused pipeline v4, MI355X (gfx950), fp16 MFMA + f32 accumulate.
//   1. x1 = relu(x @ fc1_w + b)           -> xh[:, 0:256]   (LDS-staged B)
//   2. GRU as ONE interleaved-gate GEMM [N,512]@[512,1024] + fused gates
//   3. t = relu(hn @ hg_w1 + b)            (LDS-staged B)
//   4. g = tanh(t @ hg_w2 + b)             (LDS-staged B)
//   5. q = b_dyn + sum_h hn[:,h]*(g @ hw_w[:,h,:] + hw_b)
//      final: ring-3 LDS pipeline, counted vmcnt(4) (T3/T4), hn slice in LDS,
//      ga held resident (launch_bounds(256,1) -> ~220 VGPR, still 2 waves/EU).
// Weights pre-transposed to f16 [col][K], XOR-swizzled (k ^ ((col&7)<<3)).
// ---------------------------------------------------------------------------

typedef _Float16 half8 __attribute__((ext_vector_type(8)));
typedef float f32x4 __attribute__((ext_vector_type(4)));

#define MFMA16(a, b, c) __builtin_amdgcn_mfma_f32_16x16x32_f16((a), (b), (c), 0, 0, 0)

constexpr int NROWS = 16384;

__device__ __forceinline__ float sigmoidf_(float x) { return 1.0f / (1.0f + __expf(-x)); }

__device__ __forceinline__ void glds16(const void* g, void* l) {
    __builtin_amdgcn_global_load_lds((const __attribute__((address_space(1))) void*)g,
                                     (__attribute__((address_space(3))) void*)l, 16, 0, 0);
}

// ---------------- prep: x -> x16, h -> xh[:,256:512] ----------------
__global__ void cvt_kernel(const float* __restrict__ x, const float* __restrict__ h,
                           _Float16* __restrict__ x16, _Float16* __restrict__ xh) {
    int b = blockIdx.x;
    if (b < 4096) {
        int i = (b * 256 + threadIdx.x) * 4;
        float4 v = *reinterpret_cast<const float4*>(x + i);
        x16[i + 0] = (_Float16)v.x; x16[i + 1] = (_Float16)v.y;
        x16[i + 2] = (_Float16)v.z; x16[i + 3] = (_Float16)v.w;
    } else {
        int i = ((b - 4096) * 256 + threadIdx.x) * 4;
        float4 v = *reinterpret_cast<const float4*>(h + i);
        int n = i >> 8, j = i & 255;
        _Float16* o = xh + n * 512 + 256 + j;
        o[0] = (_Float16)v.x; o[1] = (_Float16)v.y;
        o[2] = (_Float16)v.z; o[3] = (_Float16)v.w;
    }
}

// ---------------- prep: unified weight transpose+swizzle (K=256 segs) ----------------
__global__ void wtrans_kernel(const float* __restrict__ s0, const float* __restrict__ s1,
                              const float* __restrict__ s2, const float* __restrict__ s3,
                              const float* __restrict__ s4, _Float16* __restrict__ d0,
                              _Float16* __restrict__ d1, _Float16* __restrict__ d2,
                              _Float16* __restrict__ d3, _Float16* __restrict__ d4) {
    __shared__ float tile[32][33];
    int b = blockIdx.x;
    const float* src; _Float16* dst; int C, idx;
    if (b < 64)       { src = s0; dst = d0; C = 256;  idx = b; }
    else if (b < 128) { src = s1; dst = d1; C = 256;  idx = b - 64; }
    else if (b < 192) { src = s2; dst = d2; C = 256;  idx = b - 128; }
    else if (b < 200) { src = s3; dst = d3; C = 32;   idx = b - 192; }
    else              { src = s4; dst = d4; C = 8192; idx = b - 200; }
    int kb = (idx & 7) * 32, cb = (idx >> 3) * 32;
    int tx = threadIdx.x, ty = threadIdx.y;  // 32 x 8
#pragma unroll
    for (int i = ty; i < 32; i += 8) tile[i][tx] = src[(kb + i) * C + cb + tx];
    __syncthreads();
#pragma unroll
    for (int i = ty; i < 32; i += 8) {
        int c = cb + i, k = kb + tx;
        dst[c * 256 + (k ^ ((c & 7) << 3))] = (_Float16)tile[tx][i];
    }
}

// ---------------- prep: GRU weight pack, coalesced tile transpose ----------------
// wgru[1024][512] f16 swizzled; row = (c>>4)*64 + gate*16 + (c&15).
// 6 jobs: (src, col_off, gate, k_off). Zero halves pre-filled by memset.
__global__ void wgru_prep_kernel(const float* __restrict__ gwih, const float* __restrict__ gwhh,
                                 _Float16* __restrict__ wgru) {
    __shared__ float tile[32][33];
    int b = blockIdx.x, job = b >> 6, idx = b & 63;
    int kb = (idx & 7) * 32, cb = (idx >> 3) * 32;
    const float* src = (job & 1) ? gwhh : gwih;
    int coff = (job >> 1) * 256;
    int gate = (job < 4) ? (job >> 1) : (2 + (job & 1));
    int koff = (job & 1) * 256;
    int tx = threadIdx.x, ty = threadIdx.y;  // 32 x 8
#pragma unroll
    for (int i = ty; i < 32; i += 8) tile[i][tx] = src[(kb + i) * 768 + coff + cb + tx];
    __syncthreads();
#pragma unroll
    for (int i = ty; i < 32; i += 8) {
        int c = cb + i;
        int row = (c >> 4) * 64 + gate * 16 + (c & 15);
        int kk = kb + tx + koff;
        wgru[row * 512 + (kk ^ ((row & 7) << 3))] = (_Float16)tile[tx][i];
    }
}

// ---------------- GEMM + bias + activation, LDS-staged B ----------------
template <int ACT>  // 1 relu, 2 tanh
__global__ __launch_bounds__(256, 2) void gemm_lds_kernel(
    const _Float16* __restrict__ Am, const _Float16* __restrict__ Wt,
    const float* __restrict__ bias, _Float16* __restrict__ out16, int ONC) {
    __shared__ _Float16 Bs[64 * 256];  // 32 KB
    const int tid = threadIdx.x, wave = tid >> 6, lane = tid & 63;
    const int r = lane & 15, kg = lane >> 4;
    const int row0 = blockIdx.x * 256 + wave * 64;
    const int col0 = blockIdx.y * 64;
    const _Float16* src = Wt + col0 * 256;
#pragma unroll
    for (int it = 0; it < 8; ++it)
        glds16(src + it * 2048 + tid * 8, Bs + it * 2048 + tid * 8);
    asm volatile("s_waitcnt vmcnt(0)" ::: "memory");
    __syncthreads();

    f32x4 z = {0.f, 0.f, 0.f, 0.f};
    f32x4 acc[4][4];
#pragma unroll
    for (int t = 0; t < 4; t++)
#pragma unroll
        for (int j = 0; j < 4; j++) acc[t][j] = z;
    const int swz = (r & 7) << 4;
#pragma unroll
    for (int kb = 0; kb < 8; kb++) {
        half8 a[4], bm[4];
#pragma unroll
        for (int t = 0; t < 4; t++)
            a[t] = *reinterpret_cast<const half8*>(Am + (row0 + t * 16 + r) * 256 + kb * 32 + kg * 8);
#pragma unroll
        for (int j = 0; j < 4; j++)
            bm[j] = *reinterpret_cast<const half8*>(
                (const char*)Bs + (j * 16 + r) * 512 + ((kb * 64 + kg * 16) ^ swz));
#pragma unroll
        for (int t = 0; t < 4; t++)
#pragma unroll
            for (int j = 0; j < 4; j++) acc[t][j] = MFMA16(a[t], bm[j], acc[t][j]);
    }
#pragma unroll
    for (int j = 0; j < 4; j++) {
        int cc = col0 + j * 16 + r;
        float bv = bias[cc];
#pragma unroll
        for (int t = 0; t < 4; t++)
#pragma unroll
            for (int i = 0; i < 4; i++) {
                int rr = row0 + t * 16 + kg * 4 + i;
                float v = acc[t][j][i] + bv;
                if (ACT == 1) v = fmaxf(v, 0.0f);
                if (ACT == 2) v = tanhf(v);
                out16[rr * ONC + cc] = (_Float16)v;
            }
    }
}

// ---------------- fused GRU: one GEMM + gate epilogue ----------------
__global__ __launch_bounds__(256, 2) void gru_kernel(
    const _Float16* __restrict__ xh, const float* __restrict__ hf,
    const _Float16* __restrict__ wgru, const float* __restrict__ bih,
    const float* __restrict__ bhh, _Float16* __restrict__ hn16) {
    __shared__ _Float16 Bs[64 * 512];  // 64 KB
    const int tid = threadIdx.x, wave = tid >> 6, lane = tid & 63;
    const int r = lane & 15, kg = lane >> 4;
    const int row0 = blockIdx.x * 256 + wave * 64;
    const int c0 = blockIdx.y * 16;
    const _Float16* src = wgru + (size_t)blockIdx.y * 64 * 512;
#pragma unroll
    for (int it = 0; it < 16; ++it)
        glds16(src + it * 2048 + tid * 8, Bs + it * 2048 + tid * 8);
    asm volatile("s_waitcnt vmcnt(0)" ::: "memory");
    __syncthreads();

    f32x4 z = {0.f, 0.f, 0.f, 0.f};
    f32x4 acc[4][4];  // [row-tile][gate]
#pragma unroll
    for (int t = 0; t < 4; t++)
#pragma unroll
        for (int j = 0; j < 4; j++) acc[t][j] = z;
    const int swz = (r & 7) << 4;
#pragma unroll
    for (int kb = 0; kb < 16; kb++) {
        half8 a[4], bm[4];
#pragma unroll
        for (int t = 0; t < 4; t++)
            a[t] = *reinterpret_cast<const half8*>(xh + (row0 + t * 16 + r) * 512 + kb * 32 + kg * 8);
#pragma unroll
        for (int j = 0; j < 4; j++)
            bm[j] = *reinterpret_cast<const half8*>(
                (const char*)Bs + (j * 16 + r) * 1024 + ((kb * 64 + kg * 16) ^ swz));
#pragma unroll
        for (int t = 0; t < 4; t++)
#pragma unroll
            for (int j = 0; j < 4; j++) acc[t][j] = MFMA16(a[t], bm[j], acc[t][j]);
    }
    const int cc = c0 + r;
    float brz = bih[cc] + bhh[cc];
    float bzz = bih[256 + cc] + bhh[256 + cc];
    float bin = bih[512 + cc], bhn = bhh[512 + cc];
#pragma unroll
    for (int t = 0; t < 4; t++)
#pragma unroll
        for (int i = 0; i < 4; i++) {
            int rr = row0 + t * 16 + kg * 4 + i;
            float rg = sigmoidf_(acc[t][0][i] + brz);
            float zg = sigmoidf_(acc[t][1][i] + bzz);
            float nn = tanhf(acc[t][2][i] + bin + rg * (acc[t][3][i] + bhn));
            float v = (1.0f - zg) * nn + zg * hf[rr * 256 + cc];
            hn16[rr * 256 + cc] = (_Float16)v;
        }
}

// ---------------- hn16 [N][256] -> hnT16 [256][N] f16, coalesced ----------------
__global__ void hnt_kernel(const _Float16* __restrict__ hn16, _Float16* __restrict__ hnT16) {
    __shared__ float tile[32][33];
    int r0 = blockIdx.x * 32, c0 = blockIdx.y * 32;
    int tx = threadIdx.x, ty = threadIdx.y;  // 32 x 8
#pragma unroll
    for (int i = ty; i < 32; i += 8) tile[i][tx] = (float)hn16[(r0 + i) * 256 + c0 + tx];
    __syncthreads();
#pragma unroll
    for (int i = ty; i < 32; i += 8)
        hnT16[(size_t)(c0 + i) * NROWS + r0 + tx] = (_Float16)tile[tx][i];
}

// ---------------- fused final stage: ring-3 pipeline, counted vmcnt ----------------
// 1-D grid 512; by = bid&7 (XCD-pinned h-slice), bx = bid>>3 (row block).
// Wave = 64 rows x 32 actions; ga resident (~220 VGPR); hn slice f16 in LDS.
__global__ __launch_bounds__(256, 1) void final_kernel(
    const _Float16* __restrict__ g16, const _Float16* __restrict__ hwt,
    const float* __restrict__ hwb, const _Float16* __restrict__ hbt,
    const float* __restrict__ hbb, const _Float16* __restrict__ hnT16,
    float* __restrict__ q) {
    __shared__ _Float16 Bs[3][8192];   // 48 KB ring, 1 h per chunk
    __shared__ _Float16 hvs[8192];     // 16 KB: hn[rows 256][h 32] as [h][row]
    __shared__ float hwbs[1024];       // 4 KB
    const int bid = blockIdx.x;
    const int by = bid & 7, bx = bid >> 3;
    const int tid = threadIdx.x, wave = tid >> 6, lane = tid & 63;
    const int r = lane & 15, kg = lane >> 4;
    const int row0 = bx * 256 + wave * 64;
    const int hbase = by * 32;
    const int swz = (r & 7) << 4;

    // ---- issue all prologue stages (counted later) ----
#pragma unroll
    for (int it = 0; it < 4; ++it) {  // hn slice: 32 h x 256 rows f16
        int e = it * 2048 + tid * 8;
        glds16(hnT16 + (size_t)(hbase + (e >> 8)) * NROWS + bx * 256 + (e & 255), hvs + e);
    }
    glds16(hwb + hbase * 32 + tid * 4, hwbs + tid * 4);  // 4 KB f32
#pragma unroll
    for (int it = 0; it < 4; ++it) {  // chunk 0
        int e = it * 2048 + tid * 8;
        glds16(hwt + (size_t)hbase * 8192 + e, &Bs[0][0] + e);
    }
#pragma unroll
    for (int it = 0; it < 4; ++it) {  // chunk 1
        int e = it * 2048 + tid * 8;
        glds16(hwt + (size_t)(hbase + 1) * 8192 + e, &Bs[1][0] + e);
    }

    // ---- hoist g fragments: 4 row-tiles x full K=256 (128 VGPR, resident) ----
    half8 ga[4][8];
#pragma unroll
    for (int t = 0; t < 4; t++)
#pragma unroll
        for (int kb = 0; kb < 8; kb++)
            ga[t][kb] = *reinterpret_cast<const half8*>(g16 + (row0 + t * 16 + r) * 256 + kb * 32 + kg * 8);

    // ---- qa init: b_dyn on by==0, else zero ----
    f32x4 qa[4][2];
    if (by == 0) {
        float b0v = hbb[r], b1v = hbb[16 + r];
#pragma unroll
        for (int t = 0; t < 4; t++) {
            qa[t][0] = {b0v, b0v, b0v, b0v};
            qa[t][1] = {b1v, b1v, b1v, b1v};
        }
#pragma unroll
        for (int kb = 0; kb < 8; kb++) {
            const int c0b = (kb * 64 + kg * 16) ^ swz;
            half8 hb0 = *reinterpret_cast<const half8*>((const char*)hbt + r * 512 + c0b);
            half8 hb1 = *reinterpret_cast<const half8*>((const char*)hbt + (16 + r) * 512 + c0b);
#pragma unroll
            for (int t = 0; t < 4; t++) {
                qa[t][0] = MFMA16(ga[t][kb], hb0, qa[t][0]);
                qa[t][1] = MFMA16(ga[t][kb], hb1, qa[t][1]);
            }
        }
    } else {
        f32x4 z = {0.f, 0.f, 0.f, 0.f};
#pragma unroll
        for (int t = 0; t < 4; t++) { qa[t][0] = z; qa[t][1] = z; }
    }

    // ---- main loop: per h, one barrier, counted vmcnt (never 0 until tail) ----
    int cur = 0;  // h % 3
    for (int h = 0; h < 32; ++h) {
        if (h < 30)
            asm volatile("s_waitcnt vmcnt(4)" ::: "memory");
        else
            asm volatile("s_waitcnt vmcnt(0)" ::: "memory");
        __builtin_amdgcn_s_barrier();
        if (h < 30) {  // prefetch chunk h+2 into buf (cur+2)%3
            int pre = cur + 2; if (pre >= 3) pre -= 3;
            const _Float16* src = hwt + (size_t)(hbase + h + 2) * 8192;
            _Float16* dst = &Bs[pre][0];
#pragma unroll
            for (int it = 0; it < 4; ++it) {
                int e = it * 2048 + tid * 8;
                glds16(src + e, dst + e);
            }
        }
        const char* bp = (const char*)&Bs[cur][0];
        float wb0 = hwbs[h * 32 + r], wb1 = hwbs[h * 32 + 16 + r];
        f32x4 w[4][2];
#pragma unroll
        for (int t = 0; t < 4; t++) {
            w[t][0] = {wb0, wb0, wb0, wb0};
            w[t][1] = {wb1, wb1, wb1, wb1};
        }
#pragma unroll
        for (int kb = 0; kb < 8; kb++) {
            const int c0b = (kb * 64 + kg * 16) ^ swz;
            half8 b0 = *reinterpret_cast<const half8*>(bp + r * 512 + c0b);
            half8 b1 = *reinterpret_cast<const half8*>(bp + (16 + r) * 512 + c0b);
#pragma unroll
            for (int t = 0; t < 4; t++) {
                w[t][0] = MFMA16(ga[t][kb], b0, w[t][0]);
                w[t][1] = MFMA16(ga[t][kb], b1, w[t][1]);
            }
        }
#pragma unroll
        for (int t = 0; t < 4; t++) {
            const _Float16* hp = hvs + h * 256 + wave * 64 + t * 16 + kg * 4;
            f32x4 hv = {(float)hp[0], (float)hp[1], (float)hp[2], (float)hp[3]};
#pragma unroll
            for (int i = 0; i < 4; i++) {
                qa[t][0][i] += hv[i] * w[t][0][i];
                qa[t][1][i] += hv[i] * w[t][1][i];
            }
        }
        cur = cur + 1; if (cur >= 3) cur -= 3;
    }

#pragma unroll
    for (int t = 0; t < 4; t++)
#pragma unroll
        for (int i = 0; i < 4; i++) {
            int rr = row0 + t * 16 + kg * 4 + i;
            atomicAdd(&q[rr * 32 + r], qa[t][0][i]);
            atomicAdd(&q[rr * 32 + 16 + r], qa[t][1][i]);
        }
}

// ---------------------------------------------------------------------------
extern "C" void kernel_launch(void* const* d_in, const int* in_sizes, int n_in,
                              void* d_out, int out_size, void* d_ws, size_t ws_size,
                              hipStream_t stream) {
    const float* x = (const float*)d_in[0];
    const float* h = (const float*)d_in[1];
    const float* fc1_w = (const float*)d_in[2];
    const float* fc1_b = (const float*)d_in[3];
    const float* gwih = (const float*)d_in[4];
    const float* gbih = (const float*)d_in[5];
    const float* gwhh = (const float*)d_in[6];
    const float* gbhh = (const float*)d_in[7];
    const float* hgw1 = (const float*)d_in[8];
    const float* hgb1 = (const float*)d_in[9];
    const float* hgw2 = (const float*)d_in[10];
    const float* hgb2 = (const float*)d_in[11];
    const float* hbw = (const float*)d_in[12];
    const float* hbb = (const float*)d_in[13];
    const float* hww = (const float*)d_in[14];
    const float* hwb = (const float*)d_in[15];
    float* q = (float*)d_out;

    char* p = (char*)d_ws;
    auto alloc = [&](size_t bytes) { char* r = p; p += (bytes + 255) & ~255ULL; return r; };
    _Float16* x16 = (_Float16*)alloc((size_t)NROWS * 256 * 2);
    _Float16* xh = (_Float16*)alloc((size_t)NROWS * 512 * 2);
    _Float16* w1t = (_Float16*)alloc((size_t)256 * 256 * 2);
    _Float16* wgru = (_Float16*)alloc((size_t)1024 * 512 * 2);
    _Float16* hg1t = (_Float16*)alloc((size_t)256 * 256 * 2);
    _Float16* hg2t = (_Float16*)alloc((size_t)256 * 256 * 2);
    _Float16* hbt = (_Float16*)alloc((size_t)32 * 256 * 2);
    _Float16* hwt = (_Float16*)alloc((size_t)8192 * 256 * 2);
    _Float16* hn16 = (_Float16*)alloc((size_t)NROWS * 256 * 2);
    _Float16* hnT16 = (_Float16*)alloc((size_t)256 * NROWS * 2);
    _Float16* t16 = (_Float16*)alloc((size_t)NROWS * 256 * 2);
    _Float16* g16 = (_Float16*)alloc((size_t)NROWS * 256 * 2);

    // ---- prep ----
    cvt_kernel<<<8192, 256, 0, stream>>>(x, h, x16, xh);
    wtrans_kernel<<<2248, dim3(32, 8), 0, stream>>>(fc1_w, hgw1, hgw2, hbw, hww,
                                                    w1t, hg1t, hg2t, hbt, hwt);
    hipMemsetAsync(wgru, 0, (size_t)1024 * 512 * 2, stream);
    wgru_prep_kernel<<<384, dim3(32, 8), 0, stream>>>(gwih, gwhh, wgru);

    hipMemsetAsync(d_out, 0, (size_t)NROWS * 32 * sizeof(float), stream);

    // ---- stage 1: x1 = relu(x @ fc1_w + b) -> xh[:, 0:256] ----
    gemm_lds_kernel<1><<<dim3(64, 4), 256, 0, stream>>>(x16, w1t, fc1_b, xh, 512);

    // ---- stage 2: GRU ----
    gru_kernel<<<dim3(64, 16), 256, 0, stream>>>(xh, h, wgru, gbih, gbhh, hn16);
    hnt_kernel<<<dim3(512, 8), dim3(32, 8), 0, stream>>>(hn16, hnT16);

    // ---- stage 3/4: hypernet latent ----
    gemm_lds_kernel<1><<<dim3(64, 4), 256, 0, stream>>>(hn16, hg1t, hgb1, t16, 256);
    gemm_lds_kernel<2><<<dim3(64, 4), 256, 0, stream>>>(t16, hg2t, hgb2, g16, 256);

    // ---- stage 5: fused b_dyn + w_dyn einsum ----
    final_kernel<<<512, 256, 0, stream>>>(g16, hwt, hwb, hbt, hbb, hnT16, q);
}

// Round 5
// 184.097 us; speedup vs baseline: 2.4115x; 1.0056x over previous
//
#include <hip/hip_runtime.h>

// ---------------------------------------------------------------------------
// GroupAgent fused pipeline v5, MI355X (gfx950), fp16 MFMA + f32 accumulate.
//   1. x1 = relu(x @ fc1_w + b)           -> xh[:, 0:256]   (LDS-staged B)
//   2. GRU as ONE interleaved-gate GEMM [N,512]@[512,1024] + fused gates
//   3. t = relu(hn @ hg_w1 + b)            (LDS-staged B)
//   4. g = tanh(t @ hg_w2 + b)             (LDS-staged B)
//   5. q = b_dyn + sum_h hn[:,h]*(g @ hw_w[:,h,:] + hw_b)
//      final: ring-3 LDS pipeline, counted vmcnt(4); ga held RESIDENT via
//      amdgpu_waves_per_eu(2,2) (256-VGPR budget) + asm reg pins (defeats
//      the compiler's load-rematerialization that kept VGPR at 128).
// Weights pre-transposed to f16 [col][K], XOR-swizzled (k ^ ((col&7)<<3)).
// ---------------------------------------------------------------------------

typedef _Float16 half8 __attribute__((ext_vector_type(8)));
typedef _Float16 half4 __attribute__((ext_vector_type(4)));
typedef float f32x4 __attribute__((ext_vector_type(4)));

#define MFMA16(a, b, c) __builtin_amdgcn_mfma_f32_16x16x32_f16((a), (b), (c), 0, 0, 0)

constexpr int NROWS = 16384;

__device__ __forceinline__ float sigmoidf_(float x) { return 1.0f / (1.0f + __expf(-x)); }

__device__ __forceinline__ void glds16(const void* g, void* l) {
    __builtin_amdgcn_global_load_lds((const __attribute__((address_space(1))) void*)g,
                                     (__attribute__((address_space(3))) void*)l, 16, 0, 0);
}

// ---------------- prep: x -> x16, h -> xh[:,256:512] ----------------
__global__ void cvt_kernel(const float* __restrict__ x, const float* __restrict__ h,
                           _Float16* __restrict__ x16, _Float16* __restrict__ xh) {
    int b = blockIdx.x;
    if (b < 4096) {
        int i = (b * 256 + threadIdx.x) * 4;
        float4 v = *reinterpret_cast<const float4*>(x + i);
        x16[i + 0] = (_Float16)v.x; x16[i + 1] = (_Float16)v.y;
        x16[i + 2] = (_Float16)v.z; x16[i + 3] = (_Float16)v.w;
    } else {
        int i = ((b - 4096) * 256 + threadIdx.x) * 4;
        float4 v = *reinterpret_cast<const float4*>(h + i);
        int n = i >> 8, j = i & 255;
        _Float16* o = xh + n * 512 + 256 + j;
        o[0] = (_Float16)v.x; o[1] = (_Float16)v.y;
        o[2] = (_Float16)v.z; o[3] = (_Float16)v.w;
    }
}

// ---------------- prep: unified weight transpose+swizzle (K=256 segs) ----------------
__global__ void wtrans_kernel(const float* __restrict__ s0, const float* __restrict__ s1,
                              const float* __restrict__ s2, const float* __restrict__ s3,
                              const float* __restrict__ s4, _Float16* __restrict__ d0,
                              _Float16* __restrict__ d1, _Float16* __restrict__ d2,
                              _Float16* __restrict__ d3, _Float16* __restrict__ d4) {
    __shared__ float tile[32][33];
    int b = blockIdx.x;
    const float* src; _Float16* dst; int C, idx;
    if (b < 64)       { src = s0; dst = d0; C = 256;  idx = b; }
    else if (b < 128) { src = s1; dst = d1; C = 256;  idx = b - 64; }
    else if (b < 192) { src = s2; dst = d2; C = 256;  idx = b - 128; }
    else if (b < 200) { src = s3; dst = d3; C = 32;   idx = b - 192; }
    else              { src = s4; dst = d4; C = 8192; idx = b - 200; }
    int kb = (idx & 7) * 32, cb = (idx >> 3) * 32;
    int tx = threadIdx.x, ty = threadIdx.y;  // 32 x 8
#pragma unroll
    for (int i = ty; i < 32; i += 8) tile[i][tx] = src[(kb + i) * C + cb + tx];
    __syncthreads();
#pragma unroll
    for (int i = ty; i < 32; i += 8) {
        int c = cb + i, k = kb + tx;
        dst[c * 256 + (k ^ ((c & 7) << 3))] = (_Float16)tile[tx][i];
    }
}

// ---------------- prep: GRU weight pack, coalesced tile transpose ----------------
__global__ void wgru_prep_kernel(const float* __restrict__ gwih, const float* __restrict__ gwhh,
                                 _Float16* __restrict__ wgru) {
    __shared__ float tile[32][33];
    int b = blockIdx.x, job = b >> 6, idx = b & 63;
    int kb = (idx & 7) * 32, cb = (idx >> 3) * 32;
    const float* src = (job & 1) ? gwhh : gwih;
    int coff = (job >> 1) * 256;
    int gate = (job < 4) ? (job >> 1) : (2 + (job & 1));
    int koff = (job & 1) * 256;
    int tx = threadIdx.x, ty = threadIdx.y;  // 32 x 8
#pragma unroll
    for (int i = ty; i < 32; i += 8) tile[i][tx] = src[(kb + i) * 768 + coff + cb + tx];
    __syncthreads();
#pragma unroll
    for (int i = ty; i < 32; i += 8) {
        int c = cb + i;
        int row = (c >> 4) * 64 + gate * 16 + (c & 15);
        int kk = kb + tx + koff;
        wgru[row * 512 + (kk ^ ((row & 7) << 3))] = (_Float16)tile[tx][i];
    }
}

// ---------------- GEMM + bias + activation, LDS-staged B ----------------
template <int ACT>  // 1 relu, 2 tanh
__global__ __launch_bounds__(256, 2) void gemm_lds_kernel(
    const _Float16* __restrict__ Am, const _Float16* __restrict__ Wt,
    const float* __restrict__ bias, _Float16* __restrict__ out16, int ONC) {
    __shared__ _Float16 Bs[64 * 256];  // 32 KB
    const int tid = threadIdx.x, wave = tid >> 6, lane = tid & 63;
    const int r = lane & 15, kg = lane >> 4;
    const int row0 = blockIdx.x * 256 + wave * 64;
    const int col0 = blockIdx.y * 64;
    const _Float16* src = Wt + col0 * 256;
#pragma unroll
    for (int it = 0; it < 8; ++it)
        glds16(src + it * 2048 + tid * 8, Bs + it * 2048 + tid * 8);
    asm volatile("s_waitcnt vmcnt(0)" ::: "memory");
    __syncthreads();

    f32x4 z = {0.f, 0.f, 0.f, 0.f};
    f32x4 acc[4][4];
#pragma unroll
    for (int t = 0; t < 4; t++)
#pragma unroll
        for (int j = 0; j < 4; j++) acc[t][j] = z;
    const int swz = (r & 7) << 4;
#pragma unroll
    for (int kb = 0; kb < 8; kb++) {
        half8 a[4], bm[4];
#pragma unroll
        for (int t = 0; t < 4; t++)
            a[t] = *reinterpret_cast<const half8*>(Am + (row0 + t * 16 + r) * 256 + kb * 32 + kg * 8);
#pragma unroll
        for (int j = 0; j < 4; j++)
            bm[j] = *reinterpret_cast<const half8*>(
                (const char*)Bs + (j * 16 + r) * 512 + ((kb * 64 + kg * 16) ^ swz));
#pragma unroll
        for (int t = 0; t < 4; t++)
#pragma unroll
            for (int j = 0; j < 4; j++) acc[t][j] = MFMA16(a[t], bm[j], acc[t][j]);
    }
#pragma unroll
    for (int j = 0; j < 4; j++) {
        int cc = col0 + j * 16 + r;
        float bv = bias[cc];
#pragma unroll
        for (int t = 0; t < 4; t++)
#pragma unroll
            for (int i = 0; i < 4; i++) {
                int rr = row0 + t * 16 + kg * 4 + i;
                float v = acc[t][j][i] + bv;
                if (ACT == 1) v = fmaxf(v, 0.0f);
                if (ACT == 2) v = tanhf(v);
                out16[rr * ONC + cc] = (_Float16)v;
            }
    }
}

// ---------------- fused GRU: one GEMM + gate epilogue ----------------
__global__ __launch_bounds__(256, 2) void gru_kernel(
    const _Float16* __restrict__ xh, const float* __restrict__ hf,
    const _Float16* __restrict__ wgru, const float* __restrict__ bih,
    const float* __restrict__ bhh, _Float16* __restrict__ hn16) {
    __shared__ _Float16 Bs[64 * 512];  // 64 KB
    const int tid = threadIdx.x, wave = tid >> 6, lane = tid & 63;
    const int r = lane & 15, kg = lane >> 4;
    const int row0 = blockIdx.x * 256 + wave * 64;
    const int c0 = blockIdx.y * 16;
    const _Float16* src = wgru + (size_t)blockIdx.y * 64 * 512;
#pragma unroll
    for (int it = 0; it < 16; ++it)
        glds16(src + it * 2048 + tid * 8, Bs + it * 2048 + tid * 8);
    asm volatile("s_waitcnt vmcnt(0)" ::: "memory");
    __syncthreads();

    f32x4 z = {0.f, 0.f, 0.f, 0.f};
    f32x4 acc[4][4];  // [row-tile][gate]
#pragma unroll
    for (int t = 0; t < 4; t++)
#pragma unroll
        for (int j = 0; j < 4; j++) acc[t][j] = z;
    const int swz = (r & 7) << 4;
#pragma unroll
    for (int kb = 0; kb < 16; kb++) {
        half8 a[4], bm[4];
#pragma unroll
        for (int t = 0; t < 4; t++)
            a[t] = *reinterpret_cast<const half8*>(xh + (row0 + t * 16 + r) * 512 + kb * 32 + kg * 8);
#pragma unroll
        for (int j = 0; j < 4; j++)
            bm[j] = *reinterpret_cast<const half8*>(
                (const char*)Bs + (j * 16 + r) * 1024 + ((kb * 64 + kg * 16) ^ swz));
#pragma unroll
        for (int t = 0; t < 4; t++)
#pragma unroll
            for (int j = 0; j < 4; j++) acc[t][j] = MFMA16(a[t], bm[j], acc[t][j]);
    }
    const int cc = c0 + r;
    float brz = bih[cc] + bhh[cc];
    float bzz = bih[256 + cc] + bhh[256 + cc];
    float bin = bih[512 + cc], bhn = bhh[512 + cc];
#pragma unroll
    for (int t = 0; t < 4; t++)
#pragma unroll
        for (int i = 0; i < 4; i++) {
            int rr = row0 + t * 16 + kg * 4 + i;
            float rg = sigmoidf_(acc[t][0][i] + brz);
            float zg = sigmoidf_(acc[t][1][i] + bzz);
            float nn = tanhf(acc[t][2][i] + bin + rg * (acc[t][3][i] + bhn));
            float v = (1.0f - zg) * nn + zg * hf[rr * 256 + cc];
            hn16[rr * 256 + cc] = (_Float16)v;
        }
}

// ---------------- hn16 [N][256] -> hnT16 [256][N] f16, coalesced ----------------
__global__ void hnt_kernel(const _Float16* __restrict__ hn16, _Float16* __restrict__ hnT16) {
    __shared__ float tile[32][33];
    int r0 = blockIdx.x * 32, c0 = blockIdx.y * 32;
    int tx = threadIdx.x, ty = threadIdx.y;  // 32 x 8
#pragma unroll
    for (int i = ty; i < 32; i += 8) tile[i][tx] = (float)hn16[(r0 + i) * 256 + c0 + tx];
    __syncthreads();
#pragma unroll
    for (int i = ty; i < 32; i += 8)
        hnT16[(size_t)(c0 + i) * NROWS + r0 + tx] = (_Float16)tile[tx][i];
}

// ---------------- fused final stage: ring-3 pipeline, counted vmcnt ----------------
// 1-D grid 512; by = bid&7 (XCD-pinned h-slice), bx = bid>>3 (row block).
// Wave = 64 rows x 32 actions; ga RESIDENT: waves_per_eu(2,2) gives a 256-VGPR
// budget (2 blocks/CU), asm pins make the loads non-rematerializable.
__global__ __launch_bounds__(256)
__attribute__((amdgpu_waves_per_eu(2, 2))) void final_kernel(
    const _Float16* __restrict__ g16, const _Float16* __restrict__ hwt,
    const float* __restrict__ hwb, const _Float16* __restrict__ hbt,
    const float* __restrict__ hbb, const _Float16* __restrict__ hnT16,
    float* __restrict__ q) {
    __shared__ _Float16 Bs[3][8192];   // 48 KB ring, 1 h per chunk
    __shared__ _Float16 hvs[8192];     // 16 KB: hn slice as [h 32][row 256]
    __shared__ float hwbs[1024];       // 4 KB
    const int bid = blockIdx.x;
    const int by = bid & 7, bx = bid >> 3;
    const int tid = threadIdx.x, wave = tid >> 6, lane = tid & 63;
    const int r = lane & 15, kg = lane >> 4;
    const int row0 = bx * 256 + wave * 64;
    const int hbase = by * 32;
    const int swz = (r & 7) << 4;

    // ---- issue all prologue stages (counted later) ----
#pragma unroll
    for (int it = 0; it < 4; ++it) {  // hn slice: 32 h x 256 rows f16
        int e = it * 2048 + tid * 8;
        glds16(hnT16 + (size_t)(hbase + (e >> 8)) * NROWS + bx * 256 + (e & 255), hvs + e);
    }
    glds16(hwb + hbase * 32 + tid * 4, hwbs + tid * 4);  // 4 KB f32
#pragma unroll
    for (int it = 0; it < 4; ++it) {  // chunk 0
        int e = it * 2048 + tid * 8;
        glds16(hwt + (size_t)hbase * 8192 + e, &Bs[0][0] + e);
    }
#pragma unroll
    for (int it = 0; it < 4; ++it) {  // chunk 1
        int e = it * 2048 + tid * 8;
        glds16(hwt + (size_t)(hbase + 1) * 8192 + e, &Bs[1][0] + e);
    }

    // ---- hoist g fragments: 4 row-tiles x full K=256, pinned resident ----
    half8 ga[4][8];
#pragma unroll
    for (int t = 0; t < 4; t++)
#pragma unroll
        for (int kb = 0; kb < 8; kb++) {
            ga[t][kb] = *reinterpret_cast<const half8*>(
                g16 + (row0 + t * 16 + r) * 256 + kb * 32 + kg * 8);
            asm volatile("" : "+v"(ga[t][kb]));  // non-rematerializable
        }

    // ---- qa init: b_dyn on by==0, else zero ----
    f32x4 qa[4][2];
    if (by == 0) {
        float b0v = hbb[r], b1v = hbb[16 + r];
#pragma unroll
        for (int t = 0; t < 4; t++) {
            qa[t][0] = {b0v, b0v, b0v, b0v};
            qa[t][1] = {b1v, b1v, b1v, b1v};
        }
#pragma unroll
        for (int kb = 0; kb < 8; kb++) {
            const int c0b = (kb * 64 + kg * 16) ^ swz;
            half8 hb0 = *reinterpret_cast<const half8*>((const char*)hbt + r * 512 + c0b);
            half8 hb1 = *reinterpret_cast<const half8*>((const char*)hbt + (16 + r) * 512 + c0b);
#pragma unroll
            for (int t = 0; t < 4; t++) {
                qa[t][0] = MFMA16(ga[t][kb], hb0, qa[t][0]);
                qa[t][1] = MFMA16(ga[t][kb], hb1, qa[t][1]);
            }
        }
    } else {
        f32x4 z = {0.f, 0.f, 0.f, 0.f};
#pragma unroll
        for (int t = 0; t < 4; t++) { qa[t][0] = z; qa[t][1] = z; }
    }

    // ---- main loop: per h, one barrier, counted vmcnt (never 0 until tail) ----
    int cur = 0;  // h % 3
    for (int h = 0; h < 32; ++h) {
        if (h < 30)
            asm volatile("s_waitcnt vmcnt(4)" ::: "memory");
        else
            asm volatile("s_waitcnt vmcnt(0)" ::: "memory");
        __builtin_amdgcn_s_barrier();
        if (h < 30) {  // prefetch chunk h+2 into buf (cur+2)%3
            int pre = cur + 2; if (pre >= 3) pre -= 3;
            const _Float16* src = hwt + (size_t)(hbase + h + 2) * 8192;
            _Float16* dst = &Bs[pre][0];
#pragma unroll
            for (int it = 0; it < 4; ++it) {
                int e = it * 2048 + tid * 8;
                glds16(src + e, dst + e);
            }
        }
        const char* bp = (const char*)&Bs[cur][0];
        float wb0 = hwbs[h * 32 + r], wb1 = hwbs[h * 32 + 16 + r];
        f32x4 w[4][2];
#pragma unroll
        for (int t = 0; t < 4; t++) {
            w[t][0] = {wb0, wb0, wb0, wb0};
            w[t][1] = {wb1, wb1, wb1, wb1};
        }
#pragma unroll
        for (int kb = 0; kb < 8; kb++) {
            const int c0b = (kb * 64 + kg * 16) ^ swz;
            half8 b0 = *reinterpret_cast<const half8*>(bp + r * 512 + c0b);
            half8 b1 = *reinterpret_cast<const half8*>(bp + (16 + r) * 512 + c0b);
#pragma unroll
            for (int t = 0; t < 4; t++) {
                w[t][0] = MFMA16(ga[t][kb], b0, w[t][0]);
                w[t][1] = MFMA16(ga[t][kb], b1, w[t][1]);
            }
        }
#pragma unroll
        for (int t = 0; t < 4; t++) {
            half4 hv4 = *reinterpret_cast<const half4*>(hvs + h * 256 + wave * 64 + t * 16 + kg * 4);
#pragma unroll
            for (int i = 0; i < 4; i++) {
                float hvf = (float)hv4[i];
                qa[t][0][i] += hvf * w[t][0][i];
                qa[t][1][i] += hvf * w[t][1][i];
            }
        }
        cur = cur + 1; if (cur >= 3) cur -= 3;
    }

#pragma unroll
    for (int t = 0; t < 4; t++)
#pragma unroll
        for (int i = 0; i < 4; i++) {
            int rr = row0 + t * 16 + kg * 4 + i;
            atomicAdd(&q[rr * 32 + r], qa[t][0][i]);
            atomicAdd(&q[rr * 32 + 16 + r], qa[t][1][i]);
        }
}

// ---------------------------------------------------------------------------
extern "C" void kernel_launch(void* const* d_in, const int* in_sizes, int n_in,
                              void* d_out, int out_size, void* d_ws, size_t ws_size,
                              hipStream_t stream) {
    const float* x = (const float*)d_in[0];
    const float* h = (const float*)d_in[1];
    const float* fc1_w = (const float*)d_in[2];
    const float* fc1_b = (const float*)d_in[3];
    const float* gwih = (const float*)d_in[4];
    const float* gbih = (const float*)d_in[5];
    const float* gwhh = (const float*)d_in[6];
    const float* gbhh = (const float*)d_in[7];
    const float* hgw1 = (const float*)d_in[8];
    const float* hgb1 = (const float*)d_in[9];
    const float* hgw2 = (const float*)d_in[10];
    const float* hgb2 = (const float*)d_in[11];
    const float* hbw = (const float*)d_in[12];
    const float* hbb = (const float*)d_in[13];
    const float* hww = (const float*)d_in[14];
    const float* hwb = (const float*)d_in[15];
    float* q = (float*)d_out;

    char* p = (char*)d_ws;
    auto alloc = [&](size_t bytes) { char* r = p; p += (bytes + 255) & ~255ULL; return r; };
    _Float16* x16 = (_Float16*)alloc((size_t)NROWS * 256 * 2);
    _Float16* xh = (_Float16*)alloc((size_t)NROWS * 512 * 2);
    _Float16* w1t = (_Float16*)alloc((size_t)256 * 256 * 2);
    _Float16* wgru = (_Float16*)alloc((size_t)1024 * 512 * 2);
    _Float16* hg1t = (_Float16*)alloc((size_t)256 * 256 * 2);
    _Float16* hg2t = (_Float16*)alloc((size_t)256 * 256 * 2);
    _Float16* hbt = (_Float16*)alloc((size_t)32 * 256 * 2);
    _Float16* hwt = (_Float16*)alloc((size_t)8192 * 256 * 2);
    _Float16* hn16 = (_Float16*)alloc((size_t)NROWS * 256 * 2);
    _Float16* hnT16 = (_Float16*)alloc((size_t)256 * NROWS * 2);
    _Float16* t16 = (_Float16*)alloc((size_t)NROWS * 256 * 2);
    _Float16* g16 = (_Float16*)alloc((size_t)NROWS * 256 * 2);

    // ---- prep ----
    cvt_kernel<<<8192, 256, 0, stream>>>(x, h, x16, xh);
    wtrans_kernel<<<2248, dim3(32, 8), 0, stream>>>(fc1_w, hgw1, hgw2, hbw, hww,
                                                    w1t, hg1t, hg2t, hbt, hwt);
    hipMemsetAsync(wgru, 0, (size_t)1024 * 512 * 2, stream);
    wgru_prep_kernel<<<384, dim3(32, 8), 0, stream>>>(gwih, gwhh, wgru);

    hipMemsetAsync(d_out, 0, (size_t)NROWS * 32 * sizeof(float), stream);

    // ---- stage 1: x1 = relu(x @ fc1_w + b) -> xh[:, 0:256] ----
    gemm_lds_kernel<1><<<dim3(64, 4), 256, 0, stream>>>(x16, w1t, fc1_b, xh, 512);

    // ---- stage 2: GRU ----
    gru_kernel<<<dim3(64, 16), 256, 0, stream>>>(xh, h, wgru, gbih, gbhh, hn16);
    hnt_kernel<<<dim3(512, 8), dim3(32, 8), 0, stream>>>(hn16, hnT16);

    // ---- stage 3/4: hypernet latent ----
    gemm_lds_kernel<1><<<dim3(64, 4), 256, 0, stream>>>(hn16, hg1t, hgb1, t16, 256);
    gemm_lds_kernel<2><<<dim3(64, 4), 256, 0, stream>>>(t16, hg2t, hgb2, g16, 256);

    // ---- stage 5: fused b_dyn + w_dyn einsum ----
    final_kernel<<<512, 256, 0, stream>>>(g16, hwt, hwb, hbt, hbb, hnT16, q);
}